// Round 8
// baseline (119.906 us; speedup 1.0000x reference)
//
#include <hip/hip_runtime.h>
#include <hip/hip_bf16.h>

// ---------------------------------------------------------------------------
// AAttn (area attention) fused pipeline for MI355X (gfx950)
//  x:(4,256,64,64) -> qkv conv1x1 (bf16 out, + V in NCHW) -> attention
//  (16 areas x 8 heads, Na=1024, hd=32, swapped-operand MFMA flash, online
//  max) -> pe_conv (dwconv7 on V) -> proj conv1x1 (A = attn+pe)
// Workspace (64 MiB exactly):
//   QKV bf16 [16384][768]  25.17MB @ 0
//   AOUT f32 [16384][256]  16.78MB @ 25165824
//   VT   bf16 [1024][4096]  8.39MB @ 41943040   (b*256+c major)
//   PE   f32 [1024][4096]  16.78MB @ 50331648
// GEMM grids are 1D with an XCD swizzle: blocks sharing a row-panel get ids
// congruent mod 8 (same XCD L2) AND temporally adjacent:
//   id(r,c) = (r%8) + 8*c + 8*C*(r/8)   (C = #col-groups)
// ---------------------------------------------------------------------------

typedef __attribute__((ext_vector_type(8))) short bf16x8;
typedef __attribute__((ext_vector_type(4))) short bf16x4;
typedef __attribute__((ext_vector_type(8))) unsigned short u16x8;
typedef __attribute__((ext_vector_type(4))) float f32x4;
typedef unsigned short u16;

__device__ __forceinline__ short f2bf(float f) {
    unsigned u = __builtin_bit_cast(unsigned, f);
    u = u + 0x7fffu + ((u >> 16) & 1u);   // RNE
    return (short)(u >> 16);
}
__device__ __forceinline__ float bf2f(u16 u) {
    return __builtin_bit_cast(float, (unsigned)u << 16);
}
__device__ __forceinline__ float fexp2(float x) {
#if __has_builtin(__builtin_amdgcn_exp2f)
    return __builtin_amdgcn_exp2f(x);
#else
    return exp2f(x);
#endif
}
__device__ __forceinline__ unsigned cvt_pk_bf16(float lo, float hi) {
    unsigned r;
    asm("v_cvt_pk_bf16_f32 %0, %1, %2" : "=v"(r) : "v"(lo), "v"(hi));
    return r;
}

// ---------------------------------------------------------------------------
// Kernel 1: QKV GEMM -> bf16 QKV buffer, plus V replicated to NCHW bf16 (Vt).
// 1D grid 3072, XCD-swizzled: 12 col-blocks of a row-panel share an XCD.
// ---------------------------------------------------------------------------
__global__ __launch_bounds__(256) void qkv_gemm(const float* __restrict__ X,
                                                const float* __restrict__ W,
                                                const float* __restrict__ bias,
                                                u16* __restrict__ out,
                                                u16* __restrict__ Vt) {
    __shared__ short Alds[64][40];
    __shared__ short Blds[64][40];
    const int t = threadIdx.x;
    const int wv = t >> 6, lane = t & 63;
    const int g = lane >> 4, cc = lane & 15;
    // swizzled decode: id = (r%8) + 8*c + 96*(r/8),  r=0..255, c=0..11
    const int wg = blockIdx.x;
    const int hi = wg / 96, rem = wg % 96;
    const int R0 = (hi * 8 + (rem & 7)) * 64;
    const int col0 = (rem >> 3) * 64;
    const int b = R0 >> 12, n0 = R0 & 4095;
    f32x4 acc[4] = {};

    const int a_kk = t >> 4;
    const int a_ii = (t & 15) * 4;
    const int b_col = t >> 2;
    const int b_kp  = (t & 3) * 8;

    for (int k0 = 0; k0 < 256; k0 += 32) {
        __syncthreads();
        #pragma unroll
        for (int it = 0; it < 2; ++it) {
            const int kk = a_kk + it * 16;
            const float4 v = *reinterpret_cast<const float4*>(
                X + (((size_t)(b * 256 + k0 + kk)) << 12) + n0 + a_ii);
            Alds[a_ii + 0][kk] = f2bf(v.x);
            Alds[a_ii + 1][kk] = f2bf(v.y);
            Alds[a_ii + 2][kk] = f2bf(v.z);
            Alds[a_ii + 3][kk] = f2bf(v.w);
        }
        {
            const float* wp = W + (size_t)(col0 + b_col) * 256 + k0 + b_kp;
            const float4 v0 = *reinterpret_cast<const float4*>(wp);
            const float4 v1 = *reinterpret_cast<const float4*>(wp + 4);
            bf16x8 pk;
            pk[0] = f2bf(v0.x); pk[1] = f2bf(v0.y); pk[2] = f2bf(v0.z); pk[3] = f2bf(v0.w);
            pk[4] = f2bf(v1.x); pk[5] = f2bf(v1.y); pk[6] = f2bf(v1.z); pk[7] = f2bf(v1.w);
            *reinterpret_cast<bf16x8*>(&Blds[b_col][b_kp]) = pk;
        }
        __syncthreads();
        const bf16x8 af = *reinterpret_cast<const bf16x8*>(&Alds[wv * 16 + cc][g * 8]);
        #pragma unroll
        for (int nt = 0; nt < 4; ++nt) {
            const bf16x8 bfr = *reinterpret_cast<const bf16x8*>(&Blds[nt * 16 + cc][g * 8]);
            acc[nt] = __builtin_amdgcn_mfma_f32_16x16x32_bf16(af, bfr, acc[nt], 0, 0, 0);
        }
    }
    #pragma unroll
    for (int nt = 0; nt < 4; ++nt) {
        const int col = col0 + nt * 16 + cc;
        const float bv = bias[col];
        const int m96 = col % 96;
        const bool isv = (m96 >= 64);
        const int vc = (col / 96) * 32 + (m96 - 64);
        #pragma unroll
        for (int r = 0; r < 4; ++r) {
            const int row = R0 + wv * 16 + g * 4 + r;
            const u16 val = (u16)f2bf(acc[nt][r] + bv);
            out[(size_t)row * 768 + col] = val;
            if (isv)
                Vt[(((size_t)(b * 256 + vc)) << 12) + (row & 4095)] = val;
        }
    }
}

// ---------------------------------------------------------------------------
// Kernel 2: flash attention, swapped-operand MFMA.  (round-7 text, frozen)
//   grid (8 h, 8 qc, 16 ba); 4 waves; each wave: 2 q-sets x 16 q rows (q=cc).
//   KVBLK=64.  S^T = mfma(A=K, B=Q) -> P lane-local -> O^T = mfma(A=V^T, B=P^T).
// ---------------------------------------------------------------------------
__global__ __launch_bounds__(256) void attn_kernel(const u16* __restrict__ QKV,
                                                   float* __restrict__ aout) {
    __shared__ u16 Klds[64][32];
    __shared__ u16 Vlds[32][68];
    const int t = threadIdx.x;
    const int wv = t >> 6, lane = t & 63;
    const int g = lane >> 4, cc = lane & 15;
    const int h  = blockIdx.x;   // 0..7   (fastest -> determines XCD)
    const int qc = blockIdx.y;   // 0..7  (128 q rows per block)
    const int ba = blockIdx.z;   // 0..15
    const float SCALE = 0.17677669529663687f * 1.44269504088896340736f;
    const size_t base = (size_t)ba * 1024 * 768 + h * 96;

    bf16x8 qf[2];
    #pragma unroll
    for (int s = 0; s < 2; ++s) {
        const u16x8 qr = *reinterpret_cast<const u16x8*>(
            QKV + base + (size_t)(qc * 128 + s * 64 + wv * 16 + cc) * 768 + g * 8);
        #pragma unroll
        for (int j = 0; j < 8; ++j) qf[s][j] = f2bf(bf2f(qr[j]) * SCALE);
    }

    f32x4 o[2][2] = {};
    float m[2] = {-3e38f, -3e38f}, l[2] = {0.f, 0.f};

    const int key_s = t >> 2;
    const int dp    = (t & 3) * 8;
    const u16* kgp = QKV + base + 32 + (size_t)key_s * 768 + dp;
    const u16* vgp = kgp + 32;

    u16x8 kpre = *reinterpret_cast<const u16x8*>(kgp);
    u16x8 vpre = *reinterpret_cast<const u16x8*>(vgp);

    for (int kt = 0; kt < 16; ++kt) {
        __syncthreads();
        *reinterpret_cast<u16x8*>(&Klds[key_s][dp]) = kpre;
        #pragma unroll
        for (int i = 0; i < 8; ++i) Vlds[dp + i][key_s] = vpre[i];
        __syncthreads();
        if (kt < 15) {   // prefetch next tile into regs
            kpre = *reinterpret_cast<const u16x8*>(kgp + (size_t)(kt + 1) * 64 * 768);
            vpre = *reinterpret_cast<const u16x8*>(vgp + (size_t)(kt + 1) * 64 * 768);
        }

        bf16x8 kf[4];
        #pragma unroll
        for (int t16 = 0; t16 < 4; ++t16)
            kf[t16] = *reinterpret_cast<const bf16x8*>(&Klds[t16 * 16 + cc][g * 8]);
        bf16x8 va[2][2];
        #pragma unroll
        for (int hh = 0; hh < 2; ++hh)
            #pragma unroll
            for (int kg = 0; kg < 2; ++kg) {
                const bf16x4 lo = *reinterpret_cast<const bf16x4*>(&Vlds[hh * 16 + cc][kg * 32 + 4 * g]);
                const bf16x4 hi = *reinterpret_cast<const bf16x4*>(&Vlds[hh * 16 + cc][kg * 32 + 16 + 4 * g]);
                va[hh][kg] = __builtin_shufflevector(lo, hi, 0, 1, 2, 3, 4, 5, 6, 7);
            }

        #pragma unroll
        for (int s = 0; s < 2; ++s) {
            const f32x4 z = {};
            f32x4 sc[4];
            #pragma unroll
            for (int t16 = 0; t16 < 4; ++t16)
                sc[t16] = __builtin_amdgcn_mfma_f32_16x16x32_bf16(kf[t16], qf[s], z, 0, 0, 0);

            float mt = sc[0][0];
            #pragma unroll
            for (int t16 = 0; t16 < 4; ++t16)
                #pragma unroll
                for (int r = 0; r < 4; ++r) mt = fmaxf(mt, sc[t16][r]);
            mt = fmaxf(mt, __shfl_xor(mt, 16, 64));
            mt = fmaxf(mt, __shfl_xor(mt, 32, 64));
            const float mn = fmaxf(m[s], mt);
            const float fac = fexp2(m[s] - mn);
            m[s] = mn;

            float p[4][4];
            float rs = 0.f;
            #pragma unroll
            for (int t16 = 0; t16 < 4; ++t16)
                #pragma unroll
                for (int r = 0; r < 4; ++r) {
                    p[t16][r] = fexp2(sc[t16][r] - mn);
                    rs += p[t16][r];
                }
            rs += __shfl_xor(rs, 16, 64);
            rs += __shfl_xor(rs, 32, 64);
            l[s] = l[s] * fac + rs;
            o[s][0] *= fac;
            o[s][1] *= fac;

            union PW { int w[4]; bf16x8 v; } pb0, pb1;
            pb0.w[0] = (int)cvt_pk_bf16(p[0][0], p[0][1]);
            pb0.w[1] = (int)cvt_pk_bf16(p[0][2], p[0][3]);
            pb0.w[2] = (int)cvt_pk_bf16(p[1][0], p[1][1]);
            pb0.w[3] = (int)cvt_pk_bf16(p[1][2], p[1][3]);
            pb1.w[0] = (int)cvt_pk_bf16(p[2][0], p[2][1]);
            pb1.w[1] = (int)cvt_pk_bf16(p[2][2], p[2][3]);
            pb1.w[2] = (int)cvt_pk_bf16(p[3][0], p[3][1]);
            pb1.w[3] = (int)cvt_pk_bf16(p[3][2], p[3][3]);

            o[s][0] = __builtin_amdgcn_mfma_f32_16x16x32_bf16(va[0][0], pb0.v, o[s][0], 0, 0, 0);
            o[s][0] = __builtin_amdgcn_mfma_f32_16x16x32_bf16(va[0][1], pb1.v, o[s][0], 0, 0, 0);
            o[s][1] = __builtin_amdgcn_mfma_f32_16x16x32_bf16(va[1][0], pb0.v, o[s][1], 0, 0, 0);
            o[s][1] = __builtin_amdgcn_mfma_f32_16x16x32_bf16(va[1][1], pb1.v, o[s][1], 0, 0, 0);
        }
    }

    #pragma unroll
    for (int s = 0; s < 2; ++s) {
        const float inv = 1.f / l[s];
        const int q = qc * 128 + s * 64 + wv * 16 + cc;
        float* op = aout + (size_t)(ba * 1024 + q) * 256 + h * 32;
        f32x4 st0 = o[s][0] * inv;
        f32x4 st1 = o[s][1] * inv;
        *reinterpret_cast<f32x4*>(op + 4 * g)      = st0;
        *reinterpret_cast<f32x4*>(op + 16 + 4 * g) = st1;
    }
}

// ---------------------------------------------------------------------------
// Kernel 3: pe_conv.  pebuf[b][c][n] = dwconv7(Vt plane) + b_pe[c].  (frozen)
// ---------------------------------------------------------------------------
__global__ __launch_bounds__(256) void pe_conv(const u16* __restrict__ Vt,
                                               const float* __restrict__ wpe,
                                               const float* __restrict__ bpe,
                                               float* __restrict__ pebuf) {
    __shared__ __align__(16) float P[70][76];
    const int t = threadIdx.x;
    const int bc = blockIdx.x;             // b*256 + c
    const int c = bc & 255;

    {
        f32x4 z = {};
        f32x4* p4 = reinterpret_cast<f32x4*>(&P[0][0]);
        #pragma unroll
        for (int i = 0; i < 6; ++i) {
            const int idx = t + i * 256;
            if (idx < 1330) p4[idx] = z;
        }
    }
    __syncthreads();
    {
        const int row = t >> 2, xo = (t & 3) * 16;
        const u16* src = Vt + (((size_t)bc) << 12) + row * 64 + xo;
        const u16x8 v0 = *reinterpret_cast<const u16x8*>(src);
        const u16x8 v1 = *reinterpret_cast<const u16x8*>(src + 8);
        #pragma unroll
        for (int j = 0; j < 8; ++j) {
            P[row + 3][xo + 3 + j]  = bf2f(v0[j]);
            P[row + 3][xo + 11 + j] = bf2f(v1[j]);
        }
    }
    float wk[49];
    #pragma unroll
    for (int i = 0; i < 49; ++i) wk[i] = wpe[c * 49 + i];
    const float bias = bpe[c];
    __syncthreads();

    const int y = t >> 2, x0 = (t & 3) * 16;
    float acc[16];
    #pragma unroll
    for (int j = 0; j < 16; ++j) acc[j] = bias;

    #pragma unroll
    for (int dy = 0; dy < 7; ++dy) {
        float win[24];
        #pragma unroll
        for (int w4 = 0; w4 < 6; ++w4)
            *reinterpret_cast<f32x4*>(&win[w4 * 4]) =
                *reinterpret_cast<const f32x4*>(&P[y + dy][x0 + w4 * 4]);
        #pragma unroll
        for (int dx = 0; dx < 7; ++dx) {
            const float wgt = wk[dy * 7 + dx];
            #pragma unroll
            for (int xx = 0; xx < 16; ++xx)
                acc[xx] = fmaf(wgt, win[xx + dx], acc[xx]);
        }
    }

    float* dst = pebuf + (((size_t)bc) << 12) + y * 64 + x0;
    #pragma unroll
    for (int w4 = 0; w4 < 4; ++w4)
        *reinterpret_cast<f32x4*>(dst + w4 * 4) =
            *reinterpret_cast<const f32x4*>(&acc[w4 * 4]);
}

// ---------------------------------------------------------------------------
// Kernel 4: proj GEMM.  A = aout[n][k] + pebuf[k][n]; out NCHW via LDS transpose.
// 1D grid 1024, XCD-swizzled: 4 col-blocks of a row-panel share an XCD.
// ---------------------------------------------------------------------------
__global__ __launch_bounds__(256) void proj_gemm(const float* __restrict__ A,
                                                 const float* __restrict__ PE,
                                                 const float* __restrict__ W,
                                                 const float* __restrict__ bias,
                                                 float* __restrict__ out) {
    __shared__ union {
        struct { short A[64][40]; short B[64][40]; } s;
        float T[64][65];
    } u;
    const int t = threadIdx.x;
    const int wv = t >> 6, lane = t & 63;
    const int g = lane >> 4, cc = lane & 15;
    // swizzled decode: id = (r%8) + 8*c + 32*(r/8),  r=0..255, c=0..3
    const int wg = blockIdx.x;
    const int hi = wg / 32, rem = wg % 32;
    const int R0 = (hi * 8 + (rem & 7)) * 64;
    const int col0 = (rem >> 3) * 64;
    const int b = R0 >> 12, n0 = R0 & 4095;
    const int a_i  = t >> 2;
    const int a_kp = (t & 3) * 8;
    f32x4 acc[4] = {};

    for (int k0 = 0; k0 < 256; k0 += 32) {
        __syncthreads();
        {
            const float* ap = A + (size_t)(R0 + a_i) * 256 + k0 + a_kp;
            const float4 v0 = *reinterpret_cast<const float4*>(ap);
            const float4 v1 = *reinterpret_cast<const float4*>(ap + 4);
            const float* pp = PE + (((size_t)(b * 256 + k0 + a_kp)) << 12) + n0 + a_i;
            bf16x8 pk;
            pk[0] = f2bf(v0.x + pp[0]);
            pk[1] = f2bf(v0.y + pp[(size_t)1 << 12]);
            pk[2] = f2bf(v0.z + pp[(size_t)2 << 12]);
            pk[3] = f2bf(v0.w + pp[(size_t)3 << 12]);
            pk[4] = f2bf(v1.x + pp[(size_t)4 << 12]);
            pk[5] = f2bf(v1.y + pp[(size_t)5 << 12]);
            pk[6] = f2bf(v1.z + pp[(size_t)6 << 12]);
            pk[7] = f2bf(v1.w + pp[(size_t)7 << 12]);
            *reinterpret_cast<bf16x8*>(&u.s.A[a_i][a_kp]) = pk;

            const float* wp = W + (size_t)(col0 + a_i) * 256 + k0 + a_kp;
            const float4 w0 = *reinterpret_cast<const float4*>(wp);
            const float4 w1 = *reinterpret_cast<const float4*>(wp + 4);
            bf16x8 pw;
            pw[0] = f2bf(w0.x); pw[1] = f2bf(w0.y); pw[2] = f2bf(w0.z); pw[3] = f2bf(w0.w);
            pw[4] = f2bf(w1.x); pw[5] = f2bf(w1.y); pw[6] = f2bf(w1.z); pw[7] = f2bf(w1.w);
            *reinterpret_cast<bf16x8*>(&u.s.B[a_i][a_kp]) = pw;
        }
        __syncthreads();
        const bf16x8 af = *reinterpret_cast<const bf16x8*>(&u.s.A[wv * 16 + cc][g * 8]);
        #pragma unroll
        for (int nt = 0; nt < 4; ++nt) {
            const bf16x8 bfr = *reinterpret_cast<const bf16x8*>(&u.s.B[nt * 16 + cc][g * 8]);
            acc[nt] = __builtin_amdgcn_mfma_f32_16x16x32_bf16(af, bfr, acc[nt], 0, 0, 0);
        }
    }
    __syncthreads();
    #pragma unroll
    for (int nt = 0; nt < 4; ++nt) {
        const float bv = bias[col0 + nt * 16 + cc];
        #pragma unroll
        for (int r = 0; r < 4; ++r)
            u.T[nt * 16 + cc][wv * 16 + g * 4 + r] = acc[nt][r] + bv;
    }
    __syncthreads();
    #pragma unroll
    for (int it = 0; it < 16; ++it) {
        const int idx = it * 256 + t;
        const int ccc = idx >> 6, rr = idx & 63;
        out[(((size_t)(b * 256 + col0 + ccc)) << 12) + n0 + rr] = u.T[ccc][rr];
    }
}

// ---------------------------------------------------------------------------
extern "C" void kernel_launch(void* const* d_in, const int* in_sizes, int n_in,
                              void* d_out, int out_size, void* d_ws, size_t ws_size,
                              hipStream_t stream) {
    const float* x      = (const float*)d_in[0];
    const float* w_qkv  = (const float*)d_in[1];
    const float* b_qkv  = (const float*)d_in[2];
    const float* w_pe   = (const float*)d_in[3];
    const float* b_pe   = (const float*)d_in[4];
    const float* w_proj = (const float*)d_in[5];
    const float* b_proj = (const float*)d_in[6];
    float* out = (float*)d_out;

    char* ws = (char*)d_ws;
    u16*   qkvbuf = (u16*)ws;                                  // 25,165,824 B
    float* aout   = (float*)(ws + 25165824);                   // 16,777,216 B
    u16*   vt     = (u16*)(ws + 41943040);                     //  8,388,608 B
    float* pebuf  = (float*)(ws + 50331648);                   // 16,777,216 B

    qkv_gemm<<<3072, 256, 0, stream>>>(x, w_qkv, b_qkv, qkvbuf, vt);
    attn_kernel<<<dim3(8, 8, 16), 256, 0, stream>>>(qkvbuf, aout);
    pe_conv<<<1024, 256, 0, stream>>>(vt, w_pe, b_pe, pebuf);
    proj_gemm<<<1024, 256, 0, stream>>>(aout, pebuf, w_proj, b_proj, out);
}

// Round 12
// 119.439 us; speedup vs baseline: 1.0039x; 1.0039x over previous
//
#include <hip/hip_runtime.h>
#include <hip/hip_bf16.h>

// ---------------------------------------------------------------------------
// AAttn (area attention) fused pipeline for MI355X (gfx950)
//  x -> qkv conv1x1 (QK bf16 + V in NCHW bf16) -> split-K flash attention
//  (2x512 keys, f32 unnormalized partials, r8-frozen online-max softmax)
//  -> pe_conv (dwconv7 on V, f32, written over dead QK region) -> proj
//  conv1x1 with exact f32 split-K combine fused into A-staging.
// Workspace (60.8 MB of 64 MiB), temporal reuse @0:
//   QK  bf16 [16384][512] @0        16.78MB  (dead after attn)
//   PE  f32  [1024][4096] @0        16.78MB  (pe_conv writes after attn)
//   O0  f32  [16384][256] @16777216 16.78MB  (keys   0..511, unnormalized)
//   O1  f32  [16384][256] @33554432 16.78MB  (keys 512..1023)
//   VT  bf16 [1024][4096] @50331648  8.39MB  (b*256+c major)
//   L0/M0/L1/M1 f32 [131072] @58720256/59244544/59768832/60293120
// ---------------------------------------------------------------------------

typedef __attribute__((ext_vector_type(8))) short bf16x8;
typedef __attribute__((ext_vector_type(4))) short bf16x4;
typedef __attribute__((ext_vector_type(8))) unsigned short u16x8;
typedef __attribute__((ext_vector_type(4))) float f32x4;
typedef unsigned short u16;

__device__ __forceinline__ short f2bf(float f) {
    unsigned u = __builtin_bit_cast(unsigned, f);
    u = u + 0x7fffu + ((u >> 16) & 1u);   // RNE
    return (short)(u >> 16);
}
__device__ __forceinline__ float bf2f(u16 u) {
    return __builtin_bit_cast(float, (unsigned)u << 16);
}
__device__ __forceinline__ float fexp2(float x) {
#if __has_builtin(__builtin_amdgcn_exp2f)
    return __builtin_amdgcn_exp2f(x);
#else
    return exp2f(x);
#endif
}
__device__ __forceinline__ unsigned cvt_pk_bf16(float lo, float hi) {
    unsigned r;
    asm("v_cvt_pk_bf16_f32 %0, %1, %2" : "=v"(r) : "v"(lo), "v"(hi));
    return r;
}

// ---------------------------------------------------------------------------
// Kernel 1: QKV GEMM -> QK bf16 [16384][512] (col = head*64 + {0..31 Q,
// 32..63 K}) + V to NCHW VT.  Core = r8 frozen; epilogue routes per column.
// 1D grid 3072, XCD-swizzled.
// ---------------------------------------------------------------------------
__global__ __launch_bounds__(256) void qkv_gemm(const float* __restrict__ X,
                                                const float* __restrict__ W,
                                                const float* __restrict__ bias,
                                                u16* __restrict__ qkout,
                                                u16* __restrict__ Vt) {
    __shared__ short Alds[64][40];
    __shared__ short Blds[64][40];
    const int t = threadIdx.x;
    const int wv = t >> 6, lane = t & 63;
    const int g = lane >> 4, cc = lane & 15;
    const int wg = blockIdx.x;
    const int hi = wg / 96, rem = wg % 96;
    const int R0 = (hi * 8 + (rem & 7)) * 64;
    const int col0 = (rem >> 3) * 64;
    const int b = R0 >> 12, n0 = R0 & 4095;
    f32x4 acc[4] = {};

    const int a_kk = t >> 4;
    const int a_ii = (t & 15) * 4;
    const int b_col = t >> 2;
    const int b_kp  = (t & 3) * 8;

    for (int k0 = 0; k0 < 256; k0 += 32) {
        __syncthreads();
        #pragma unroll
        for (int it = 0; it < 2; ++it) {
            const int kk = a_kk + it * 16;
            const float4 v = *reinterpret_cast<const float4*>(
                X + (((size_t)(b * 256 + k0 + kk)) << 12) + n0 + a_ii);
            Alds[a_ii + 0][kk] = f2bf(v.x);
            Alds[a_ii + 1][kk] = f2bf(v.y);
            Alds[a_ii + 2][kk] = f2bf(v.z);
            Alds[a_ii + 3][kk] = f2bf(v.w);
        }
        {
            const float* wp = W + (size_t)(col0 + b_col) * 256 + k0 + b_kp;
            const float4 v0 = *reinterpret_cast<const float4*>(wp);
            const float4 v1 = *reinterpret_cast<const float4*>(wp + 4);
            bf16x8 pk;
            pk[0] = f2bf(v0.x); pk[1] = f2bf(v0.y); pk[2] = f2bf(v0.z); pk[3] = f2bf(v0.w);
            pk[4] = f2bf(v1.x); pk[5] = f2bf(v1.y); pk[6] = f2bf(v1.z); pk[7] = f2bf(v1.w);
            *reinterpret_cast<bf16x8*>(&Blds[b_col][b_kp]) = pk;
        }
        __syncthreads();
        const bf16x8 af = *reinterpret_cast<const bf16x8*>(&Alds[wv * 16 + cc][g * 8]);
        #pragma unroll
        for (int nt = 0; nt < 4; ++nt) {
            const bf16x8 bfr = *reinterpret_cast<const bf16x8*>(&Blds[nt * 16 + cc][g * 8]);
            acc[nt] = __builtin_amdgcn_mfma_f32_16x16x32_bf16(af, bfr, acc[nt], 0, 0, 0);
        }
    }
    #pragma unroll
    for (int nt = 0; nt < 4; ++nt) {
        const int col = col0 + nt * 16 + cc;
        const float bv = bias[col];
        const int m96 = col % 96;
        const int head = col / 96;
        const bool isv = (m96 >= 64);
        #pragma unroll
        for (int r = 0; r < 4; ++r) {
            const int row = R0 + wv * 16 + g * 4 + r;
            const u16 val = (u16)f2bf(acc[nt][r] + bv);
            if (isv)
                Vt[(((size_t)(b * 256 + head * 32 + (m96 - 64))) << 12) + (row & 4095)] = val;
            else
                qkout[(size_t)row * 512 + head * 64 + m96] = val;
        }
    }
}

// ---------------------------------------------------------------------------
// Kernel 2: split-K flash attention.  Softmax = r8 frozen verbatim.
// K from QK buffer; V staged DIRECTLY from VT (coalesced, no transpose).
//   grid (8 h, 8 qc, 32 = ba*2+half); 8 tiles of 64 keys per block.
// Outputs per half: O f32 unnormalized [row][256], l,m f32 [row*8+h].
// ---------------------------------------------------------------------------
__global__ __launch_bounds__(256) void attn_kernel(const u16* __restrict__ QK,
                                                   const u16* __restrict__ VT,
                                                   float* __restrict__ O0,
                                                   float* __restrict__ O1,
                                                   float* __restrict__ L0,
                                                   float* __restrict__ M0,
                                                   float* __restrict__ L1,
                                                   float* __restrict__ M1) {
    __shared__ u16 Klds[64][32];
    __shared__ u16 Vlds[32][68];
    const int t = threadIdx.x;
    const int wv = t >> 6, lane = t & 63;
    const int g = lane >> 4, cc = lane & 15;
    const int h  = blockIdx.x;           // 0..7   (fastest -> determines XCD)
    const int qc = blockIdx.y;           // 0..7  (128 q rows per block)
    const int zz = blockIdx.z;           // 0..31
    const int ba = zz >> 1, half = zz & 1;
    const int koff = half * 512;
    float* Oh = half ? O1 : O0;
    float* Lh = half ? L1 : L0;
    float* Mh = half ? M1 : M0;
    const float SCALE = 0.17677669529663687f * 1.44269504088896340736f;
    const size_t qkbase = (size_t)(ba * 1024) * 512 + h * 64;

    bf16x8 qf[2];
    #pragma unroll
    for (int s = 0; s < 2; ++s) {
        const u16x8 qr = *reinterpret_cast<const u16x8*>(
            QK + qkbase + (size_t)(qc * 128 + s * 64 + wv * 16 + cc) * 512 + g * 8);
        #pragma unroll
        for (int j = 0; j < 8; ++j) qf[s][j] = f2bf(bf2f(qr[j]) * SCALE);
    }

    f32x4 o[2][2] = {};
    float m[2] = {-3e38f, -3e38f}, l[2] = {0.f, 0.f};

    // K staging: thread -> (key_s, dp)
    const int key_s = t >> 2;            // 0..63
    const int dp    = (t & 3) * 8;       // 0,8,16,24
    const u16* kgp = QK + qkbase + (size_t)(koff + key_s) * 512 + 32 + dp;
    // V staging from VT: thread -> (vd, vx8); coalesced along keys
    const int vd  = t >> 3;              // 0..31
    const int vx8 = (t & 7) * 8;         // 0..56
    const int b_img = ba >> 2, area = ba & 3;
    const u16* vgp = VT + (((size_t)(b_img * 256 + h * 32 + vd)) << 12)
                        + area * 1024 + koff + vx8;

    u16x8 kpre = *reinterpret_cast<const u16x8*>(kgp);
    u16x8 vpre = *reinterpret_cast<const u16x8*>(vgp);

    for (int kt = 0; kt < 8; ++kt) {
        __syncthreads();
        *reinterpret_cast<u16x8*>(&Klds[key_s][dp]) = kpre;
        *reinterpret_cast<u16x8*>(&Vlds[vd][vx8])   = vpre;
        __syncthreads();
        if (kt < 7) {   // prefetch next tile into regs
            kpre = *reinterpret_cast<const u16x8*>(kgp + (size_t)(kt + 1) * 64 * 512);
            vpre = *reinterpret_cast<const u16x8*>(vgp + (kt + 1) * 64);
        }

        bf16x8 kf[4];
        #pragma unroll
        for (int t16 = 0; t16 < 4; ++t16)
            kf[t16] = *reinterpret_cast<const bf16x8*>(&Klds[t16 * 16 + cc][g * 8]);
        bf16x8 va[2][2];
        #pragma unroll
        for (int hh = 0; hh < 2; ++hh)
            #pragma unroll
            for (int kg = 0; kg < 2; ++kg) {
                const bf16x4 lo = *reinterpret_cast<const bf16x4*>(&Vlds[hh * 16 + cc][kg * 32 + 4 * g]);
                const bf16x4 hi = *reinterpret_cast<const bf16x4*>(&Vlds[hh * 16 + cc][kg * 32 + 16 + 4 * g]);
                va[hh][kg] = __builtin_shufflevector(lo, hi, 0, 1, 2, 3, 4, 5, 6, 7);
            }

        #pragma unroll
        for (int s = 0; s < 2; ++s) {
            const f32x4 z = {};
            f32x4 sc[4];
            #pragma unroll
            for (int t16 = 0; t16 < 4; ++t16)
                sc[t16] = __builtin_amdgcn_mfma_f32_16x16x32_bf16(kf[t16], qf[s], z, 0, 0, 0);

            float mt = sc[0][0];
            #pragma unroll
            for (int t16 = 0; t16 < 4; ++t16)
                #pragma unroll
                for (int r = 0; r < 4; ++r) mt = fmaxf(mt, sc[t16][r]);
            mt = fmaxf(mt, __shfl_xor(mt, 16, 64));
            mt = fmaxf(mt, __shfl_xor(mt, 32, 64));
            const float mn = fmaxf(m[s], mt);
            const float fac = fexp2(m[s] - mn);
            m[s] = mn;

            float p[4][4];
            float rs = 0.f;
            #pragma unroll
            for (int t16 = 0; t16 < 4; ++t16)
                #pragma unroll
                for (int r = 0; r < 4; ++r) {
                    p[t16][r] = fexp2(sc[t16][r] - mn);
                    rs += p[t16][r];
                }
            rs += __shfl_xor(rs, 16, 64);
            rs += __shfl_xor(rs, 32, 64);
            l[s] = l[s] * fac + rs;
            o[s][0] *= fac;
            o[s][1] *= fac;

            union PW { int w[4]; bf16x8 v; } pb0, pb1;
            pb0.w[0] = (int)cvt_pk_bf16(p[0][0], p[0][1]);
            pb0.w[1] = (int)cvt_pk_bf16(p[0][2], p[0][3]);
            pb0.w[2] = (int)cvt_pk_bf16(p[1][0], p[1][1]);
            pb0.w[3] = (int)cvt_pk_bf16(p[1][2], p[1][3]);
            pb1.w[0] = (int)cvt_pk_bf16(p[2][0], p[2][1]);
            pb1.w[1] = (int)cvt_pk_bf16(p[2][2], p[2][3]);
            pb1.w[2] = (int)cvt_pk_bf16(p[3][0], p[3][1]);
            pb1.w[3] = (int)cvt_pk_bf16(p[3][2], p[3][3]);

            o[s][0] = __builtin_amdgcn_mfma_f32_16x16x32_bf16(va[0][0], pb0.v, o[s][0], 0, 0, 0);
            o[s][0] = __builtin_amdgcn_mfma_f32_16x16x32_bf16(va[0][1], pb1.v, o[s][0], 0, 0, 0);
            o[s][1] = __builtin_amdgcn_mfma_f32_16x16x32_bf16(va[1][0], pb0.v, o[s][1], 0, 0, 0);
            o[s][1] = __builtin_amdgcn_mfma_f32_16x16x32_bf16(va[1][1], pb1.v, o[s][1], 0, 0, 0);
        }
    }

    // epilogue: store unnormalized O (f32) and per-(row,head) l, m
    #pragma unroll
    for (int s = 0; s < 2; ++s) {
        const int q = qc * 128 + s * 64 + wv * 16 + cc;
        const int row = ba * 1024 + q;
        float* op = Oh + (size_t)row * 256 + h * 32;
        *reinterpret_cast<f32x4*>(op + 4 * g)      = o[s][0];   // d = 4g..4g+3
        *reinterpret_cast<f32x4*>(op + 16 + 4 * g) = o[s][1];   // d = 16+4g..+3
        if (g == 0) {
            const int idx = row * 8 + h;
            Lh[idx] = l[s];
            Mh[idx] = m[s];
        }
    }
}

// ---------------------------------------------------------------------------
// Kernel 3: pe_conv (r8 f32 version, frozen).  Writes PE over dead QK region.
// ---------------------------------------------------------------------------
__global__ __launch_bounds__(256) void pe_conv(const u16* __restrict__ Vt,
                                               const float* __restrict__ wpe,
                                               const float* __restrict__ bpe,
                                               float* __restrict__ pebuf) {
    __shared__ __align__(16) float P[70][76];
    const int t = threadIdx.x;
    const int bc = blockIdx.x;             // b*256 + c
    const int c = bc & 255;

    {
        f32x4 z = {};
        f32x4* p4 = reinterpret_cast<f32x4*>(&P[0][0]);
        #pragma unroll
        for (int i = 0; i < 6; ++i) {
            const int idx = t + i * 256;
            if (idx < 1330) p4[idx] = z;
        }
    }
    __syncthreads();
    {
        const int row = t >> 2, xo = (t & 3) * 16;
        const u16* src = Vt + (((size_t)bc) << 12) + row * 64 + xo;
        const u16x8 v0 = *reinterpret_cast<const u16x8*>(src);
        const u16x8 v1 = *reinterpret_cast<const u16x8*>(src + 8);
        #pragma unroll
        for (int j = 0; j < 8; ++j) {
            P[row + 3][xo + 3 + j]  = bf2f(v0[j]);
            P[row + 3][xo + 11 + j] = bf2f(v1[j]);
        }
    }
    float wk[49];
    #pragma unroll
    for (int i = 0; i < 49; ++i) wk[i] = wpe[c * 49 + i];
    const float bias = bpe[c];
    __syncthreads();

    const int y = t >> 2, x0 = (t & 3) * 16;
    float acc[16];
    #pragma unroll
    for (int j = 0; j < 16; ++j) acc[j] = bias;

    #pragma unroll
    for (int dy = 0; dy < 7; ++dy) {
        float win[24];
        #pragma unroll
        for (int w4 = 0; w4 < 6; ++w4)
            *reinterpret_cast<f32x4*>(&win[w4 * 4]) =
                *reinterpret_cast<const f32x4*>(&P[y + dy][x0 + w4 * 4]);
        #pragma unroll
        for (int dx = 0; dx < 7; ++dx) {
            const float wgt = wk[dy * 7 + dx];
            #pragma unroll
            for (int xx = 0; xx < 16; ++xx)
                acc[xx] = fmaf(wgt, win[xx + dx], acc[xx]);
        }
    }

    float* dst = pebuf + (((size_t)bc) << 12) + y * 64 + x0;
    #pragma unroll
    for (int w4 = 0; w4 < 4; ++w4)
        *reinterpret_cast<f32x4*>(dst + w4 * 4) =
            *reinterpret_cast<const f32x4*>(&acc[w4 * 4]);
}

// ---------------------------------------------------------------------------
// Kernel 4: proj GEMM with exact f32 split-K combine in A-staging.
//   A[row][k] = (O0*c0 + O1*c1) + PE[k][row],  c_i = f_i/(L0 f0 + L1 f1),
//   f_i = 2^(M_i - max(M0,M1)); 8-channel pack lies within one head.
// 1D grid 1024, XCD-swizzled.  Out NCHW via LDS transpose.
// ---------------------------------------------------------------------------
__global__ __launch_bounds__(256) void proj_gemm(const float* __restrict__ O0b,
                                                 const float* __restrict__ O1b,
                                                 const float* __restrict__ L0,
                                                 const float* __restrict__ M0,
                                                 const float* __restrict__ L1,
                                                 const float* __restrict__ M1,
                                                 const float* __restrict__ PE,
                                                 const float* __restrict__ W,
                                                 const float* __restrict__ bias,
                                                 float* __restrict__ out) {
    __shared__ union {
        struct { short A[64][40]; short B[64][40]; } s;
        float T[64][65];
    } u;
    const int t = threadIdx.x;
    const int wv = t >> 6, lane = t & 63;
    const int g = lane >> 4, cc = lane & 15;
    const int wg = blockIdx.x;
    const int hi = wg / 32, rem = wg % 32;
    const int R0 = (hi * 8 + (rem & 7)) * 64;
    const int col0 = (rem >> 3) * 64;
    const int b = R0 >> 12, n0 = R0 & 4095;
    const int a_i  = t >> 2;
    const int a_kp = (t & 3) * 8;
    f32x4 acc[4] = {};

    for (int k0 = 0; k0 < 256; k0 += 32) {
        __syncthreads();
        {
            const int row = R0 + a_i;
            const int hh8 = (k0 + a_kp) >> 5;       // head for these 8 channels
            const int lmix = row * 8 + hh8;
            const float M0v = M0[lmix], M1v = M1[lmix];
            const float mstar = fmaxf(M0v, M1v);
            const float f0 = fexp2(M0v - mstar);
            const float f1 = fexp2(M1v - mstar);
            const float invl = 1.0f / (L0[lmix] * f0 + L1[lmix] * f1);
            const float c0 = f0 * invl, c1 = f1 * invl;
            const float* p0 = O0b + (size_t)row * 256 + k0 + a_kp;
            const float* p1 = O1b + (size_t)row * 256 + k0 + a_kp;
            const float4 x0lo = *reinterpret_cast<const float4*>(p0);
            const float4 x0hi = *reinterpret_cast<const float4*>(p0 + 4);
            const float4 x1lo = *reinterpret_cast<const float4*>(p1);
            const float4 x1hi = *reinterpret_cast<const float4*>(p1 + 4);
            const float* pp = PE + (((size_t)(b * 256 + k0 + a_kp)) << 12) + n0 + a_i;
            bf16x8 pk;
            pk[0] = f2bf(x0lo.x * c0 + x1lo.x * c1 + pp[0]);
            pk[1] = f2bf(x0lo.y * c0 + x1lo.y * c1 + pp[(size_t)1 << 12]);
            pk[2] = f2bf(x0lo.z * c0 + x1lo.z * c1 + pp[(size_t)2 << 12]);
            pk[3] = f2bf(x0lo.w * c0 + x1lo.w * c1 + pp[(size_t)3 << 12]);
            pk[4] = f2bf(x0hi.x * c0 + x1hi.x * c1 + pp[(size_t)4 << 12]);
            pk[5] = f2bf(x0hi.y * c0 + x1hi.y * c1 + pp[(size_t)5 << 12]);
            pk[6] = f2bf(x0hi.z * c0 + x1hi.z * c1 + pp[(size_t)6 << 12]);
            pk[7] = f2bf(x0hi.w * c0 + x1hi.w * c1 + pp[(size_t)7 << 12]);
            *reinterpret_cast<bf16x8*>(&u.s.A[a_i][a_kp]) = pk;

            const float* wp = W + (size_t)(col0 + a_i) * 256 + k0 + a_kp;
            const float4 w0 = *reinterpret_cast<const float4*>(wp);
            const float4 w1 = *reinterpret_cast<const float4*>(wp + 4);
            bf16x8 pw;
            pw[0] = f2bf(w0.x); pw[1] = f2bf(w0.y); pw[2] = f2bf(w0.z); pw[3] = f2bf(w0.w);
            pw[4] = f2bf(w1.x); pw[5] = f2bf(w1.y); pw[6] = f2bf(w1.z); pw[7] = f2bf(w1.w);
            *reinterpret_cast<bf16x8*>(&u.s.B[a_i][a_kp]) = pw;
        }
        __syncthreads();
        const bf16x8 af = *reinterpret_cast<const bf16x8*>(&u.s.A[wv * 16 + cc][g * 8]);
        #pragma unroll
        for (int nt = 0; nt < 4; ++nt) {
            const bf16x8 bfr = *reinterpret_cast<const bf16x8*>(&u.s.B[nt * 16 + cc][g * 8]);
            acc[nt] = __builtin_amdgcn_mfma_f32_16x16x32_bf16(af, bfr, acc[nt], 0, 0, 0);
        }
    }
    __syncthreads();
    #pragma unroll
    for (int nt = 0; nt < 4; ++nt) {
        const float bv = bias[col0 + nt * 16 + cc];
        #pragma unroll
        for (int r = 0; r < 4; ++r)
            u.T[nt * 16 + cc][wv * 16 + g * 4 + r] = acc[nt][r] + bv;
    }
    __syncthreads();
    #pragma unroll
    for (int it = 0; it < 16; ++it) {
        const int idx = it * 256 + t;
        const int ccc = idx >> 6, rr = idx & 63;
        out[(((size_t)(b * 256 + col0 + ccc)) << 12) + n0 + rr] = u.T[ccc][rr];
    }
}

// ---------------------------------------------------------------------------
extern "C" void kernel_launch(void* const* d_in, const int* in_sizes, int n_in,
                              void* d_out, int out_size, void* d_ws, size_t ws_size,
                              hipStream_t stream) {
    const float* x      = (const float*)d_in[0];
    const float* w_qkv  = (const float*)d_in[1];
    const float* b_qkv  = (const float*)d_in[2];
    const float* w_pe   = (const float*)d_in[3];
    const float* b_pe   = (const float*)d_in[4];
    const float* w_proj = (const float*)d_in[5];
    const float* b_proj = (const float*)d_in[6];
    float* out = (float*)d_out;

    char* ws = (char*)d_ws;
    u16*   qk    = (u16*)ws;                    // 16,777,216 B (dead after attn)
    float* pe    = (float*)ws;                  // 16,777,216 B (written after attn)
    float* o0    = (float*)(ws + 16777216);     // 16,777,216 B
    float* o1    = (float*)(ws + 33554432);     // 16,777,216 B
    u16*   vt    = (u16*)(ws + 50331648);       //  8,388,608 B
    float* l0    = (float*)(ws + 58720256);     //    524,288 B
    float* m0    = (float*)(ws + 59244544);
    float* l1    = (float*)(ws + 59768832);
    float* m1    = (float*)(ws + 60293120);     // end 60,817,408

    qkv_gemm<<<3072, 256, 0, stream>>>(x, w_qkv, b_qkv, qk, vt);
    attn_kernel<<<dim3(8, 8, 32), 256, 0, stream>>>(qk, vt, o0, o1, l0, m0, l1, m1);
    pe_conv<<<1024, 256, 0, stream>>>(vt, w_pe, b_pe, pe);
    proj_gemm<<<1024, 256, 0, stream>>>(o0, o1, l0, m0, l1, m1, pe,
                                        w_proj, b_proj, out);
}

// Round 13
// 109.626 us; speedup vs baseline: 1.0938x; 1.0895x over previous
//
#include <hip/hip_runtime.h>
#include <hip/hip_bf16.h>

// ---------------------------------------------------------------------------
// AAttn (area attention) fused pipeline for MI355X (gfx950)
//  x -> qkv conv1x1 (QK bf16 + V in NCHW bf16; A-staging via packed-dword
//  channel pairs, 4-way-max LDS banks) -> split-K flash attention (2x512
//  keys, f32 unnormalized partials, r8-frozen online-max softmax) -> pe_conv
//  (dwconv7 on V, f32, written over dead QK region) -> proj conv1x1 with
//  exact f32 split-K combine fused into A-staging.
// Workspace (60.8 MB of 64 MiB), temporal reuse @0:
//   QK  bf16 [16384][512] @0        16.78MB  (dead after attn)
//   PE  f32  [1024][4096] @0        16.78MB  (pe_conv writes after attn)
//   O0  f32  [16384][256] @16777216 16.78MB  (keys   0..511, unnormalized)
//   O1  f32  [16384][256] @33554432 16.78MB  (keys 512..1023)
//   VT  bf16 [1024][4096] @50331648  8.39MB  (b*256+c major)
//   L0/M0/L1/M1 f32 [131072] @58720256/59244544/59768832/60293120
// ---------------------------------------------------------------------------

typedef __attribute__((ext_vector_type(8))) short bf16x8;
typedef __attribute__((ext_vector_type(4))) short bf16x4;
typedef __attribute__((ext_vector_type(8))) unsigned short u16x8;
typedef __attribute__((ext_vector_type(4))) float f32x4;
typedef unsigned short u16;

__device__ __forceinline__ short f2bf(float f) {
    unsigned u = __builtin_bit_cast(unsigned, f);
    u = u + 0x7fffu + ((u >> 16) & 1u);   // RNE
    return (short)(u >> 16);
}
__device__ __forceinline__ float bf2f(u16 u) {
    return __builtin_bit_cast(float, (unsigned)u << 16);
}
__device__ __forceinline__ float fexp2(float x) {
#if __has_builtin(__builtin_amdgcn_exp2f)
    return __builtin_amdgcn_exp2f(x);
#else
    return exp2f(x);
#endif
}
__device__ __forceinline__ unsigned cvt_pk_bf16(float lo, float hi) {
    unsigned r;
    asm("v_cvt_pk_bf16_f32 %0, %1, %2" : "=v"(r) : "v"(lo), "v"(hi));
    return r;
}

// ---------------------------------------------------------------------------
// Kernel 1: QKV GEMM -> QK bf16 [16384][512] + V to NCHW VT.
// A-staging: packed channel-pair dwords A32[64][22] (4-way max conflicts,
// 4 dword stores vs 8 short stores).  1D grid 3072, XCD-swizzled.
// ---------------------------------------------------------------------------
__global__ __launch_bounds__(256) void qkv_gemm(const float* __restrict__ X,
                                                const float* __restrict__ W,
                                                const float* __restrict__ bias,
                                                u16* __restrict__ qkout,
                                                u16* __restrict__ Vt) {
    __shared__ unsigned A32[64][22];   // [row(n)][chan-pair] packed 2xbf16
    __shared__ short Blds[64][40];
    const int t = threadIdx.x;
    const int wv = t >> 6, lane = t & 63;
    const int g = lane >> 4, cc = lane & 15;
    const int wg = blockIdx.x;
    const int hi = wg / 96, rem = wg % 96;
    const int R0 = (hi * 8 + (rem & 7)) * 64;
    const int col0 = (rem >> 3) * 64;
    const int b = R0 >> 12, n0 = R0 & 4095;
    f32x4 acc[4] = {};

    const int a_qi = t >> 4;          // 0..15: channel pair (2qi, 2qi+1)
    const int a_ii = (t & 15) * 4;    // rows n offset
    const int b_col = t >> 2;         // 0..63
    const int b_kp  = (t & 3) * 8;    // 0,8,16,24

    for (int k0 = 0; k0 < 256; k0 += 32) {
        __syncthreads();
        {   // stage A: 2 coalesced float4 loads (channels 2qi, 2qi+1) -> dwords
            const float* xp = X + (((size_t)(b * 256 + k0 + 2 * a_qi)) << 12) + n0 + a_ii;
            const float4 v0 = *reinterpret_cast<const float4*>(xp);
            const float4 v1 = *reinterpret_cast<const float4*>(xp + 4096);
            A32[a_ii + 0][a_qi] = cvt_pk_bf16(v0.x, v1.x);
            A32[a_ii + 1][a_qi] = cvt_pk_bf16(v0.y, v1.y);
            A32[a_ii + 2][a_qi] = cvt_pk_bf16(v0.z, v1.z);
            A32[a_ii + 3][a_qi] = cvt_pk_bf16(v0.w, v1.w);
        }
        {   // stage B: W[col][k] contiguous -> one b128 store
            const float* wp = W + (size_t)(col0 + b_col) * 256 + k0 + b_kp;
            const float4 v0 = *reinterpret_cast<const float4*>(wp);
            const float4 v1 = *reinterpret_cast<const float4*>(wp + 4);
            unsigned pk[4];
            pk[0] = cvt_pk_bf16(v0.x, v0.y);
            pk[1] = cvt_pk_bf16(v0.z, v0.w);
            pk[2] = cvt_pk_bf16(v1.x, v1.y);
            pk[3] = cvt_pk_bf16(v1.z, v1.w);
            *reinterpret_cast<uint4*>(&Blds[b_col][b_kp]) =
                *reinterpret_cast<const uint4*>(pk);
        }
        __syncthreads();
        union { unsigned u[4]; bf16x8 v; } afu;
        {
            const unsigned* ap = &A32[wv * 16 + cc][g * 4];
            const uint2 lo = *reinterpret_cast<const uint2*>(ap);
            const uint2 hi2 = *reinterpret_cast<const uint2*>(ap + 2);
            afu.u[0] = lo.x; afu.u[1] = lo.y; afu.u[2] = hi2.x; afu.u[3] = hi2.y;
        }
        #pragma unroll
        for (int nt = 0; nt < 4; ++nt) {
            const bf16x8 bfr = *reinterpret_cast<const bf16x8*>(&Blds[nt * 16 + cc][g * 8]);
            acc[nt] = __builtin_amdgcn_mfma_f32_16x16x32_bf16(afu.v, bfr, acc[nt], 0, 0, 0);
        }
    }
    #pragma unroll
    for (int nt = 0; nt < 4; ++nt) {
        const int col = col0 + nt * 16 + cc;
        const float bv = bias[col];
        const int m96 = col % 96;
        const int head = col / 96;
        const bool isv = (m96 >= 64);
        #pragma unroll
        for (int r = 0; r < 4; ++r) {
            const int row = R0 + wv * 16 + g * 4 + r;
            const u16 val = (u16)f2bf(acc[nt][r] + bv);
            if (isv)
                Vt[(((size_t)(b * 256 + head * 32 + (m96 - 64))) << 12) + (row & 4095)] = val;
            else
                qkout[(size_t)row * 512 + head * 64 + m96] = val;
        }
    }
}

// ---------------------------------------------------------------------------
// Kernel 2: split-K flash attention.  (r12 text, frozen)
// ---------------------------------------------------------------------------
__global__ __launch_bounds__(256) void attn_kernel(const u16* __restrict__ QK,
                                                   const u16* __restrict__ VT,
                                                   float* __restrict__ O0,
                                                   float* __restrict__ O1,
                                                   float* __restrict__ L0,
                                                   float* __restrict__ M0,
                                                   float* __restrict__ L1,
                                                   float* __restrict__ M1) {
    __shared__ u16 Klds[64][32];
    __shared__ u16 Vlds[32][68];
    const int t = threadIdx.x;
    const int wv = t >> 6, lane = t & 63;
    const int g = lane >> 4, cc = lane & 15;
    const int h  = blockIdx.x;           // 0..7   (fastest -> determines XCD)
    const int qc = blockIdx.y;           // 0..7  (128 q rows per block)
    const int zz = blockIdx.z;           // 0..31
    const int ba = zz >> 1, half = zz & 1;
    const int koff = half * 512;
    float* Oh = half ? O1 : O0;
    float* Lh = half ? L1 : L0;
    float* Mh = half ? M1 : M0;
    const float SCALE = 0.17677669529663687f * 1.44269504088896340736f;
    const size_t qkbase = (size_t)(ba * 1024) * 512 + h * 64;

    bf16x8 qf[2];
    #pragma unroll
    for (int s = 0; s < 2; ++s) {
        const u16x8 qr = *reinterpret_cast<const u16x8*>(
            QK + qkbase + (size_t)(qc * 128 + s * 64 + wv * 16 + cc) * 512 + g * 8);
        #pragma unroll
        for (int j = 0; j < 8; ++j) qf[s][j] = f2bf(bf2f(qr[j]) * SCALE);
    }

    f32x4 o[2][2] = {};
    float m[2] = {-3e38f, -3e38f}, l[2] = {0.f, 0.f};

    const int key_s = t >> 2;            // 0..63
    const int dp    = (t & 3) * 8;       // 0,8,16,24
    const u16* kgp = QK + qkbase + (size_t)(koff + key_s) * 512 + 32 + dp;
    const int vd  = t >> 3;              // 0..31
    const int vx8 = (t & 7) * 8;         // 0..56
    const int b_img = ba >> 2, area = ba & 3;
    const u16* vgp = VT + (((size_t)(b_img * 256 + h * 32 + vd)) << 12)
                        + area * 1024 + koff + vx8;

    u16x8 kpre = *reinterpret_cast<const u16x8*>(kgp);
    u16x8 vpre = *reinterpret_cast<const u16x8*>(vgp);

    for (int kt = 0; kt < 8; ++kt) {
        __syncthreads();
        *reinterpret_cast<u16x8*>(&Klds[key_s][dp]) = kpre;
        *reinterpret_cast<u16x8*>(&Vlds[vd][vx8])   = vpre;
        __syncthreads();
        if (kt < 7) {   // prefetch next tile into regs
            kpre = *reinterpret_cast<const u16x8*>(kgp + (size_t)(kt + 1) * 64 * 512);
            vpre = *reinterpret_cast<const u16x8*>(vgp + (kt + 1) * 64);
        }

        bf16x8 kf[4];
        #pragma unroll
        for (int t16 = 0; t16 < 4; ++t16)
            kf[t16] = *reinterpret_cast<const bf16x8*>(&Klds[t16 * 16 + cc][g * 8]);
        bf16x8 va[2][2];
        #pragma unroll
        for (int hh = 0; hh < 2; ++hh)
            #pragma unroll
            for (int kg = 0; kg < 2; ++kg) {
                const bf16x4 lo = *reinterpret_cast<const bf16x4*>(&Vlds[hh * 16 + cc][kg * 32 + 4 * g]);
                const bf16x4 hi = *reinterpret_cast<const bf16x4*>(&Vlds[hh * 16 + cc][kg * 32 + 16 + 4 * g]);
                va[hh][kg] = __builtin_shufflevector(lo, hi, 0, 1, 2, 3, 4, 5, 6, 7);
            }

        #pragma unroll
        for (int s = 0; s < 2; ++s) {
            const f32x4 z = {};
            f32x4 sc[4];
            #pragma unroll
            for (int t16 = 0; t16 < 4; ++t16)
                sc[t16] = __builtin_amdgcn_mfma_f32_16x16x32_bf16(kf[t16], qf[s], z, 0, 0, 0);

            float mt = sc[0][0];
            #pragma unroll
            for (int t16 = 0; t16 < 4; ++t16)
                #pragma unroll
                for (int r = 0; r < 4; ++r) mt = fmaxf(mt, sc[t16][r]);
            mt = fmaxf(mt, __shfl_xor(mt, 16, 64));
            mt = fmaxf(mt, __shfl_xor(mt, 32, 64));
            const float mn = fmaxf(m[s], mt);
            const float fac = fexp2(m[s] - mn);
            m[s] = mn;

            float p[4][4];
            float rs = 0.f;
            #pragma unroll
            for (int t16 = 0; t16 < 4; ++t16)
                #pragma unroll
                for (int r = 0; r < 4; ++r) {
                    p[t16][r] = fexp2(sc[t16][r] - mn);
                    rs += p[t16][r];
                }
            rs += __shfl_xor(rs, 16, 64);
            rs += __shfl_xor(rs, 32, 64);
            l[s] = l[s] * fac + rs;
            o[s][0] *= fac;
            o[s][1] *= fac;

            union PW { int w[4]; bf16x8 v; } pb0, pb1;
            pb0.w[0] = (int)cvt_pk_bf16(p[0][0], p[0][1]);
            pb0.w[1] = (int)cvt_pk_bf16(p[0][2], p[0][3]);
            pb0.w[2] = (int)cvt_pk_bf16(p[1][0], p[1][1]);
            pb0.w[3] = (int)cvt_pk_bf16(p[1][2], p[1][3]);
            pb1.w[0] = (int)cvt_pk_bf16(p[2][0], p[2][1]);
            pb1.w[1] = (int)cvt_pk_bf16(p[2][2], p[2][3]);
            pb1.w[2] = (int)cvt_pk_bf16(p[3][0], p[3][1]);
            pb1.w[3] = (int)cvt_pk_bf16(p[3][2], p[3][3]);

            o[s][0] = __builtin_amdgcn_mfma_f32_16x16x32_bf16(va[0][0], pb0.v, o[s][0], 0, 0, 0);
            o[s][0] = __builtin_amdgcn_mfma_f32_16x16x32_bf16(va[0][1], pb1.v, o[s][0], 0, 0, 0);
            o[s][1] = __builtin_amdgcn_mfma_f32_16x16x32_bf16(va[1][0], pb0.v, o[s][1], 0, 0, 0);
            o[s][1] = __builtin_amdgcn_mfma_f32_16x16x32_bf16(va[1][1], pb1.v, o[s][1], 0, 0, 0);
        }
    }

    // epilogue: store unnormalized O (f32) and per-(row,head) l, m
    #pragma unroll
    for (int s = 0; s < 2; ++s) {
        const int q = qc * 128 + s * 64 + wv * 16 + cc;
        const int row = ba * 1024 + q;
        float* op = Oh + (size_t)row * 256 + h * 32;
        *reinterpret_cast<f32x4*>(op + 4 * g)      = o[s][0];   // d = 4g..4g+3
        *reinterpret_cast<f32x4*>(op + 16 + 4 * g) = o[s][1];   // d = 16+4g..+3
        if (g == 0) {
            const int idx = row * 8 + h;
            Lh[idx] = l[s];
            Mh[idx] = m[s];
        }
    }
}

// ---------------------------------------------------------------------------
// Kernel 3: pe_conv (r12 text, frozen).  Writes PE over dead QK region.
// ---------------------------------------------------------------------------
__global__ __launch_bounds__(256) void pe_conv(const u16* __restrict__ Vt,
                                               const float* __restrict__ wpe,
                                               const float* __restrict__ bpe,
                                               float* __restrict__ pebuf) {
    __shared__ __align__(16) float P[70][76];
    const int t = threadIdx.x;
    const int bc = blockIdx.x;             // b*256 + c
    const int c = bc & 255;

    {
        f32x4 z = {};
        f32x4* p4 = reinterpret_cast<f32x4*>(&P[0][0]);
        #pragma unroll
        for (int i = 0; i < 6; ++i) {
            const int idx = t + i * 256;
            if (idx < 1330) p4[idx] = z;
        }
    }
    __syncthreads();
    {
        const int row = t >> 2, xo = (t & 3) * 16;
        const u16* src = Vt + (((size_t)bc) << 12) + row * 64 + xo;
        const u16x8 v0 = *reinterpret_cast<const u16x8*>(src);
        const u16x8 v1 = *reinterpret_cast<const u16x8*>(src + 8);
        #pragma unroll
        for (int j = 0; j < 8; ++j) {
            P[row + 3][xo + 3 + j]  = bf2f(v0[j]);
            P[row + 3][xo + 11 + j] = bf2f(v1[j]);
        }
    }
    float wk[49];
    #pragma unroll
    for (int i = 0; i < 49; ++i) wk[i] = wpe[c * 49 + i];
    const float bias = bpe[c];
    __syncthreads();

    const int y = t >> 2, x0 = (t & 3) * 16;
    float acc[16];
    #pragma unroll
    for (int j = 0; j < 16; ++j) acc[j] = bias;

    #pragma unroll
    for (int dy = 0; dy < 7; ++dy) {
        float win[24];
        #pragma unroll
        for (int w4 = 0; w4 < 6; ++w4)
            *reinterpret_cast<f32x4*>(&win[w4 * 4]) =
                *reinterpret_cast<const f32x4*>(&P[y + dy][x0 + w4 * 4]);
        #pragma unroll
        for (int dx = 0; dx < 7; ++dx) {
            const float wgt = wk[dy * 7 + dx];
            #pragma unroll
            for (int xx = 0; xx < 16; ++xx)
                acc[xx] = fmaf(wgt, win[xx + dx], acc[xx]);
        }
    }

    float* dst = pebuf + (((size_t)bc) << 12) + y * 64 + x0;
    #pragma unroll
    for (int w4 = 0; w4 < 4; ++w4)
        *reinterpret_cast<f32x4*>(dst + w4 * 4) =
            *reinterpret_cast<const f32x4*>(&acc[w4 * 4]);
}

// ---------------------------------------------------------------------------
// Kernel 4: proj GEMM with exact f32 split-K combine.  (r12 text, frozen)
// ---------------------------------------------------------------------------
__global__ __launch_bounds__(256) void proj_gemm(const float* __restrict__ O0b,
                                                 const float* __restrict__ O1b,
                                                 const float* __restrict__ L0,
                                                 const float* __restrict__ M0,
                                                 const float* __restrict__ L1,
                                                 const float* __restrict__ M1,
                                                 const float* __restrict__ PE,
                                                 const float* __restrict__ W,
                                                 const float* __restrict__ bias,
                                                 float* __restrict__ out) {
    __shared__ union {
        struct { short A[64][40]; short B[64][40]; } s;
        float T[64][65];
    } u;
    const int t = threadIdx.x;
    const int wv = t >> 6, lane = t & 63;
    const int g = lane >> 4, cc = lane & 15;
    const int wg = blockIdx.x;
    const int hi = wg / 32, rem = wg % 32;
    const int R0 = (hi * 8 + (rem & 7)) * 64;
    const int col0 = (rem >> 3) * 64;
    const int b = R0 >> 12, n0 = R0 & 4095;
    const int a_i  = t >> 2;
    const int a_kp = (t & 3) * 8;
    f32x4 acc[4] = {};

    for (int k0 = 0; k0 < 256; k0 += 32) {
        __syncthreads();
        {
            const int row = R0 + a_i;
            const int hh8 = (k0 + a_kp) >> 5;       // head for these 8 channels
            const int lmix = row * 8 + hh8;
            const float M0v = M0[lmix], M1v = M1[lmix];
            const float mstar = fmaxf(M0v, M1v);
            const float f0 = fexp2(M0v - mstar);
            const float f1 = fexp2(M1v - mstar);
            const float invl = 1.0f / (L0[lmix] * f0 + L1[lmix] * f1);
            const float c0 = f0 * invl, c1 = f1 * invl;
            const float* p0 = O0b + (size_t)row * 256 + k0 + a_kp;
            const float* p1 = O1b + (size_t)row * 256 + k0 + a_kp;
            const float4 x0lo = *reinterpret_cast<const float4*>(p0);
            const float4 x0hi = *reinterpret_cast<const float4*>(p0 + 4);
            const float4 x1lo = *reinterpret_cast<const float4*>(p1);
            const float4 x1hi = *reinterpret_cast<const float4*>(p1 + 4);
            const float* pp = PE + (((size_t)(b * 256 + k0 + a_kp)) << 12) + n0 + a_i;
            bf16x8 pk;
            pk[0] = f2bf(x0lo.x * c0 + x1lo.x * c1 + pp[0]);
            pk[1] = f2bf(x0lo.y * c0 + x1lo.y * c1 + pp[(size_t)1 << 12]);
            pk[2] = f2bf(x0lo.z * c0 + x1lo.z * c1 + pp[(size_t)2 << 12]);
            pk[3] = f2bf(x0lo.w * c0 + x1lo.w * c1 + pp[(size_t)3 << 12]);
            pk[4] = f2bf(x0hi.x * c0 + x1hi.x * c1 + pp[(size_t)4 << 12]);
            pk[5] = f2bf(x0hi.y * c0 + x1hi.y * c1 + pp[(size_t)5 << 12]);
            pk[6] = f2bf(x0hi.z * c0 + x1hi.z * c1 + pp[(size_t)6 << 12]);
            pk[7] = f2bf(x0hi.w * c0 + x1hi.w * c1 + pp[(size_t)7 << 12]);
            *reinterpret_cast<bf16x8*>(&u.s.A[a_i][a_kp]) = pk;

            const float* wp = W + (size_t)(col0 + a_i) * 256 + k0 + a_kp;
            const float4 w0 = *reinterpret_cast<const float4*>(wp);
            const float4 w1 = *reinterpret_cast<const float4*>(wp + 4);
            bf16x8 pw;
            pw[0] = f2bf(w0.x); pw[1] = f2bf(w0.y); pw[2] = f2bf(w0.z); pw[3] = f2bf(w0.w);
            pw[4] = f2bf(w1.x); pw[5] = f2bf(w1.y); pw[6] = f2bf(w1.z); pw[7] = f2bf(w1.w);
            *reinterpret_cast<bf16x8*>(&u.s.B[a_i][a_kp]) = pw;
        }
        __syncthreads();
        const bf16x8 af = *reinterpret_cast<const bf16x8*>(&u.s.A[wv * 16 + cc][g * 8]);
        #pragma unroll
        for (int nt = 0; nt < 4; ++nt) {
            const bf16x8 bfr = *reinterpret_cast<const bf16x8*>(&u.s.B[nt * 16 + cc][g * 8]);
            acc[nt] = __builtin_amdgcn_mfma_f32_16x16x32_bf16(af, bfr, acc[nt], 0, 0, 0);
        }
    }
    __syncthreads();
    #pragma unroll
    for (int nt = 0; nt < 4; ++nt) {
        const float bv = bias[col0 + nt * 16 + cc];
        #pragma unroll
        for (int r = 0; r < 4; ++r)
            u.T[nt * 16 + cc][wv * 16 + g * 4 + r] = acc[nt][r] + bv;
    }
    __syncthreads();
    #pragma unroll
    for (int it = 0; it < 16; ++it) {
        const int idx = it * 256 + t;
        const int ccc = idx >> 6, rr = idx & 63;
        out[(((size_t)(b * 256 + col0 + ccc)) << 12) + n0 + rr] = u.T[ccc][rr];
    }
}

// ---------------------------------------------------------------------------
extern "C" void kernel_launch(void* const* d_in, const int* in_sizes, int n_in,
                              void* d_out, int out_size, void* d_ws, size_t ws_size,
                              hipStream_t stream) {
    const float* x      = (const float*)d_in[0];
    const float* w_qkv  = (const float*)d_in[1];
    const float* b_qkv  = (const float*)d_in[2];
    const float* w_pe   = (const float*)d_in[3];
    const float* b_pe   = (const float*)d_in[4];
    const float* w_proj = (const float*)d_in[5];
    const float* b_proj = (const float*)d_in[6];
    float* out = (float*)d_out;

    char* ws = (char*)d_ws;
    u16*   qk    = (u16*)ws;                    // 16,777,216 B (dead after attn)
    float* pe    = (float*)ws;                  // 16,777,216 B (written after attn)
    float* o0    = (float*)(ws + 16777216);     // 16,777,216 B
    float* o1    = (float*)(ws + 33554432);     // 16,777,216 B
    u16*   vt    = (u16*)(ws + 50331648);       //  8,388,608 B
    float* l0    = (float*)(ws + 58720256);     //    524,288 B
    float* m0    = (float*)(ws + 59244544);
    float* l1    = (float*)(ws + 59768832);
    float* m1    = (float*)(ws + 60293120);     // end 60,817,408

    qkv_gemm<<<3072, 256, 0, stream>>>(x, w_qkv, b_qkv, qk, vt);
    attn_kernel<<<dim3(8, 8, 32), 256, 0, stream>>>(qk, vt, o0, o1, l0, m0, l1, m1);
    pe_conv<<<1024, 256, 0, stream>>>(vt, w_pe, b_pe, pe);
    proj_gemm<<<1024, 256, 0, stream>>>(o0, o1, l0, m0, l1, m1, pe,
                                        w_proj, b_proj, out);
}

// Round 14
// 108.616 us; speedup vs baseline: 1.1039x; 1.0093x over previous
//
#include <hip/hip_runtime.h>
#include <hip/hip_bf16.h>

// ---------------------------------------------------------------------------
// AAttn (area attention) fused pipeline for MI355X (gfx950)
//  x -> qkv conv1x1 (QK bf16 + V in NCHW bf16; packed-dword A-staging) ->
//  split-K flash attention (2x512 keys, f32 unnormalized partials, frozen
//  online-max softmax, lane-partial denominator w/ epilogue reduce) ->
//  pe_conv (dwconv7 on V, f32, over dead QK region) -> proj conv1x1 with
//  exact f32 split-K combine fused into A-staging.
// Workspace (60.8 MB of 64 MiB), temporal reuse @0:
//   QK  bf16 [16384][512] @0        16.78MB  (dead after attn)
//   PE  f32  [1024][4096] @0        16.78MB  (pe_conv writes after attn)
//   O0  f32  [16384][256] @16777216 16.78MB
//   O1  f32  [16384][256] @33554432 16.78MB
//   VT  bf16 [1024][4096] @50331648  8.39MB
//   L0/M0/L1/M1 f32 [131072] @58720256/59244544/59768832/60293120
// ---------------------------------------------------------------------------

typedef __attribute__((ext_vector_type(8))) short bf16x8;
typedef __attribute__((ext_vector_type(4))) short bf16x4;
typedef __attribute__((ext_vector_type(8))) unsigned short u16x8;
typedef __attribute__((ext_vector_type(4))) float f32x4;
typedef unsigned short u16;

__device__ __forceinline__ short f2bf(float f) {
    unsigned u = __builtin_bit_cast(unsigned, f);
    u = u + 0x7fffu + ((u >> 16) & 1u);   // RNE
    return (short)(u >> 16);
}
__device__ __forceinline__ float bf2f(u16 u) {
    return __builtin_bit_cast(float, (unsigned)u << 16);
}
__device__ __forceinline__ float fexp2(float x) {
#if __has_builtin(__builtin_amdgcn_exp2f)
    return __builtin_amdgcn_exp2f(x);
#else
    return exp2f(x);
#endif
}
__device__ __forceinline__ unsigned cvt_pk_bf16(float lo, float hi) {
    unsigned r;
    asm("v_cvt_pk_bf16_f32 %0, %1, %2" : "=v"(r) : "v"(lo), "v"(hi));
    return r;
}

// ---------------------------------------------------------------------------
// Kernel 1: QKV GEMM -> QK bf16 [16384][512] + V to NCHW VT.  (r13 frozen)
// ---------------------------------------------------------------------------
__global__ __launch_bounds__(256) void qkv_gemm(const float* __restrict__ X,
                                                const float* __restrict__ W,
                                                const float* __restrict__ bias,
                                                u16* __restrict__ qkout,
                                                u16* __restrict__ Vt) {
    __shared__ unsigned A32[64][22];   // [row(n)][chan-pair] packed 2xbf16
    __shared__ short Blds[64][40];
    const int t = threadIdx.x;
    const int wv = t >> 6, lane = t & 63;
    const int g = lane >> 4, cc = lane & 15;
    const int wg = blockIdx.x;
    const int hi = wg / 96, rem = wg % 96;
    const int R0 = (hi * 8 + (rem & 7)) * 64;
    const int col0 = (rem >> 3) * 64;
    const int b = R0 >> 12, n0 = R0 & 4095;
    f32x4 acc[4] = {};

    const int a_qi = t >> 4;          // 0..15: channel pair (2qi, 2qi+1)
    const int a_ii = (t & 15) * 4;    // rows n offset
    const int b_col = t >> 2;         // 0..63
    const int b_kp  = (t & 3) * 8;    // 0,8,16,24

    for (int k0 = 0; k0 < 256; k0 += 32) {
        __syncthreads();
        {   // stage A: 2 coalesced float4 loads (channels 2qi, 2qi+1) -> dwords
            const float* xp = X + (((size_t)(b * 256 + k0 + 2 * a_qi)) << 12) + n0 + a_ii;
            const float4 v0 = *reinterpret_cast<const float4*>(xp);
            const float4 v1 = *reinterpret_cast<const float4*>(xp + 4096);
            A32[a_ii + 0][a_qi] = cvt_pk_bf16(v0.x, v1.x);
            A32[a_ii + 1][a_qi] = cvt_pk_bf16(v0.y, v1.y);
            A32[a_ii + 2][a_qi] = cvt_pk_bf16(v0.z, v1.z);
            A32[a_ii + 3][a_qi] = cvt_pk_bf16(v0.w, v1.w);
        }
        {   // stage B: W[col][k] contiguous -> one b128 store
            const float* wp = W + (size_t)(col0 + b_col) * 256 + k0 + b_kp;
            const float4 v0 = *reinterpret_cast<const float4*>(wp);
            const float4 v1 = *reinterpret_cast<const float4*>(wp + 4);
            unsigned pk[4];
            pk[0] = cvt_pk_bf16(v0.x, v0.y);
            pk[1] = cvt_pk_bf16(v0.z, v0.w);
            pk[2] = cvt_pk_bf16(v1.x, v1.y);
            pk[3] = cvt_pk_bf16(v1.z, v1.w);
            *reinterpret_cast<uint4*>(&Blds[b_col][b_kp]) =
                *reinterpret_cast<const uint4*>(pk);
        }
        __syncthreads();
        union { unsigned u[4]; bf16x8 v; } afu;
        {
            const unsigned* ap = &A32[wv * 16 + cc][g * 4];
            const uint2 lo = *reinterpret_cast<const uint2*>(ap);
            const uint2 hi2 = *reinterpret_cast<const uint2*>(ap + 2);
            afu.u[0] = lo.x; afu.u[1] = lo.y; afu.u[2] = hi2.x; afu.u[3] = hi2.y;
        }
        #pragma unroll
        for (int nt = 0; nt < 4; ++nt) {
            const bf16x8 bfr = *reinterpret_cast<const bf16x8*>(&Blds[nt * 16 + cc][g * 8]);
            acc[nt] = __builtin_amdgcn_mfma_f32_16x16x32_bf16(afu.v, bfr, acc[nt], 0, 0, 0);
        }
    }
    #pragma unroll
    for (int nt = 0; nt < 4; ++nt) {
        const int col = col0 + nt * 16 + cc;
        const float bv = bias[col];
        const int m96 = col % 96;
        const int head = col / 96;
        const bool isv = (m96 >= 64);
        #pragma unroll
        for (int r = 0; r < 4; ++r) {
            const int row = R0 + wv * 16 + g * 4 + r;
            const u16 val = (u16)f2bf(acc[nt][r] + bv);
            if (isv)
                Vt[(((size_t)(b * 256 + head * 32 + (m96 - 64))) << 12) + (row & 4095)] = val;
            else
                qkout[(size_t)row * 512 + head * 64 + m96] = val;
        }
    }
}

// ---------------------------------------------------------------------------
// Kernel 2: split-K flash attention.  r13 text; ONE change: the per-tile
// cross-lane sum shuffles are removed — l is kept as a LANE-PARTIAL
// denominator (valid since fac is uniform across each 4-lane q-group after
// the max shuffles) and reduced once in the epilogue.
// ---------------------------------------------------------------------------
__global__ __launch_bounds__(256) void attn_kernel(const u16* __restrict__ QK,
                                                   const u16* __restrict__ VT,
                                                   float* __restrict__ O0,
                                                   float* __restrict__ O1,
                                                   float* __restrict__ L0,
                                                   float* __restrict__ M0,
                                                   float* __restrict__ L1,
                                                   float* __restrict__ M1) {
    __shared__ u16 Klds[64][32];
    __shared__ u16 Vlds[32][68];
    const int t = threadIdx.x;
    const int wv = t >> 6, lane = t & 63;
    const int g = lane >> 4, cc = lane & 15;
    const int h  = blockIdx.x;           // 0..7   (fastest -> determines XCD)
    const int qc = blockIdx.y;           // 0..7  (128 q rows per block)
    const int zz = blockIdx.z;           // 0..31
    const int ba = zz >> 1, half = zz & 1;
    const int koff = half * 512;
    float* Oh = half ? O1 : O0;
    float* Lh = half ? L1 : L0;
    float* Mh = half ? M1 : M0;
    const float SCALE = 0.17677669529663687f * 1.44269504088896340736f;
    const size_t qkbase = (size_t)(ba * 1024) * 512 + h * 64;

    bf16x8 qf[2];
    #pragma unroll
    for (int s = 0; s < 2; ++s) {
        const u16x8 qr = *reinterpret_cast<const u16x8*>(
            QK + qkbase + (size_t)(qc * 128 + s * 64 + wv * 16 + cc) * 512 + g * 8);
        #pragma unroll
        for (int j = 0; j < 8; ++j) qf[s][j] = f2bf(bf2f(qr[j]) * SCALE);
    }

    f32x4 o[2][2] = {};
    float m[2] = {-3e38f, -3e38f}, l[2] = {0.f, 0.f};   // l is lane-partial

    const int key_s = t >> 2;            // 0..63
    const int dp    = (t & 3) * 8;       // 0,8,16,24
    const u16* kgp = QK + qkbase + (size_t)(koff + key_s) * 512 + 32 + dp;
    const int vd  = t >> 3;              // 0..31
    const int vx8 = (t & 7) * 8;         // 0..56
    const int b_img = ba >> 2, area = ba & 3;
    const u16* vgp = VT + (((size_t)(b_img * 256 + h * 32 + vd)) << 12)
                        + area * 1024 + koff + vx8;

    u16x8 kpre = *reinterpret_cast<const u16x8*>(kgp);
    u16x8 vpre = *reinterpret_cast<const u16x8*>(vgp);

    for (int kt = 0; kt < 8; ++kt) {
        __syncthreads();
        *reinterpret_cast<u16x8*>(&Klds[key_s][dp]) = kpre;
        *reinterpret_cast<u16x8*>(&Vlds[vd][vx8])   = vpre;
        __syncthreads();
        if (kt < 7) {   // prefetch next tile into regs
            kpre = *reinterpret_cast<const u16x8*>(kgp + (size_t)(kt + 1) * 64 * 512);
            vpre = *reinterpret_cast<const u16x8*>(vgp + (kt + 1) * 64);
        }

        bf16x8 kf[4];
        #pragma unroll
        for (int t16 = 0; t16 < 4; ++t16)
            kf[t16] = *reinterpret_cast<const bf16x8*>(&Klds[t16 * 16 + cc][g * 8]);
        bf16x8 va[2][2];
        #pragma unroll
        for (int hh = 0; hh < 2; ++hh)
            #pragma unroll
            for (int kg = 0; kg < 2; ++kg) {
                const bf16x4 lo = *reinterpret_cast<const bf16x4*>(&Vlds[hh * 16 + cc][kg * 32 + 4 * g]);
                const bf16x4 hi = *reinterpret_cast<const bf16x4*>(&Vlds[hh * 16 + cc][kg * 32 + 16 + 4 * g]);
                va[hh][kg] = __builtin_shufflevector(lo, hi, 0, 1, 2, 3, 4, 5, 6, 7);
            }

        #pragma unroll
        for (int s = 0; s < 2; ++s) {
            const f32x4 z = {};
            f32x4 sc[4];
            #pragma unroll
            for (int t16 = 0; t16 < 4; ++t16)
                sc[t16] = __builtin_amdgcn_mfma_f32_16x16x32_bf16(kf[t16], qf[s], z, 0, 0, 0);

            float mt = sc[0][0];
            #pragma unroll
            for (int t16 = 0; t16 < 4; ++t16)
                #pragma unroll
                for (int r = 0; r < 4; ++r) mt = fmaxf(mt, sc[t16][r]);
            mt = fmaxf(mt, __shfl_xor(mt, 16, 64));
            mt = fmaxf(mt, __shfl_xor(mt, 32, 64));
            const float mn = fmaxf(m[s], mt);
            const float fac = fexp2(m[s] - mn);
            m[s] = mn;

            float p[4][4];
            float rs = 0.f;
            #pragma unroll
            for (int t16 = 0; t16 < 4; ++t16)
                #pragma unroll
                for (int r = 0; r < 4; ++r) {
                    p[t16][r] = fexp2(sc[t16][r] - mn);
                    rs += p[t16][r];
                }
            l[s] = l[s] * fac + rs;     // lane-partial (fac uniform per q-group)
            o[s][0] *= fac;
            o[s][1] *= fac;

            union PW { int w[4]; bf16x8 v; } pb0, pb1;
            pb0.w[0] = (int)cvt_pk_bf16(p[0][0], p[0][1]);
            pb0.w[1] = (int)cvt_pk_bf16(p[0][2], p[0][3]);
            pb0.w[2] = (int)cvt_pk_bf16(p[1][0], p[1][1]);
            pb0.w[3] = (int)cvt_pk_bf16(p[1][2], p[1][3]);
            pb1.w[0] = (int)cvt_pk_bf16(p[2][0], p[2][1]);
            pb1.w[1] = (int)cvt_pk_bf16(p[2][2], p[2][3]);
            pb1.w[2] = (int)cvt_pk_bf16(p[3][0], p[3][1]);
            pb1.w[3] = (int)cvt_pk_bf16(p[3][2], p[3][3]);

            o[s][0] = __builtin_amdgcn_mfma_f32_16x16x32_bf16(va[0][0], pb0.v, o[s][0], 0, 0, 0);
            o[s][0] = __builtin_amdgcn_mfma_f32_16x16x32_bf16(va[0][1], pb1.v, o[s][0], 0, 0, 0);
            o[s][1] = __builtin_amdgcn_mfma_f32_16x16x32_bf16(va[1][0], pb0.v, o[s][1], 0, 0, 0);
            o[s][1] = __builtin_amdgcn_mfma_f32_16x16x32_bf16(va[1][1], pb1.v, o[s][1], 0, 0, 0);
        }
    }

    // epilogue: reduce lane-partial l across the 4-lane q-group, store O,l,m
    #pragma unroll
    for (int s = 0; s < 2; ++s) {
        l[s] += __shfl_xor(l[s], 16, 64);
        l[s] += __shfl_xor(l[s], 32, 64);
        const int q = qc * 128 + s * 64 + wv * 16 + cc;
        const int row = ba * 1024 + q;
        float* op = Oh + (size_t)row * 256 + h * 32;
        *reinterpret_cast<f32x4*>(op + 4 * g)      = o[s][0];   // d = 4g..4g+3
        *reinterpret_cast<f32x4*>(op + 16 + 4 * g) = o[s][1];   // d = 16+4g..+3
        if (g == 0) {
            const int idx = row * 8 + h;
            Lh[idx] = l[s];
            Mh[idx] = m[s];
        }
    }
}

// ---------------------------------------------------------------------------
// Kernel 3: pe_conv (r13 text, frozen).  Writes PE over dead QK region.
// ---------------------------------------------------------------------------
__global__ __launch_bounds__(256) void pe_conv(const u16* __restrict__ Vt,
                                               const float* __restrict__ wpe,
                                               const float* __restrict__ bpe,
                                               float* __restrict__ pebuf) {
    __shared__ __align__(16) float P[70][76];
    const int t = threadIdx.x;
    const int bc = blockIdx.x;             // b*256 + c
    const int c = bc & 255;

    {
        f32x4 z = {};
        f32x4* p4 = reinterpret_cast<f32x4*>(&P[0][0]);
        #pragma unroll
        for (int i = 0; i < 6; ++i) {
            const int idx = t + i * 256;
            if (idx < 1330) p4[idx] = z;
        }
    }
    __syncthreads();
    {
        const int row = t >> 2, xo = (t & 3) * 16;
        const u16* src = Vt + (((size_t)bc) << 12) + row * 64 + xo;
        const u16x8 v0 = *reinterpret_cast<const u16x8*>(src);
        const u16x8 v1 = *reinterpret_cast<const u16x8*>(src + 8);
        #pragma unroll
        for (int j = 0; j < 8; ++j) {
            P[row + 3][xo + 3 + j]  = bf2f(v0[j]);
            P[row + 3][xo + 11 + j] = bf2f(v1[j]);
        }
    }
    float wk[49];
    #pragma unroll
    for (int i = 0; i < 49; ++i) wk[i] = wpe[c * 49 + i];
    const float bias = bpe[c];
    __syncthreads();

    const int y = t >> 2, x0 = (t & 3) * 16;
    float acc[16];
    #pragma unroll
    for (int j = 0; j < 16; ++j) acc[j] = bias;

    #pragma unroll
    for (int dy = 0; dy < 7; ++dy) {
        float win[24];
        #pragma unroll
        for (int w4 = 0; w4 < 6; ++w4)
            *reinterpret_cast<f32x4*>(&win[w4 * 4]) =
                *reinterpret_cast<const f32x4*>(&P[y + dy][x0 + w4 * 4]);
        #pragma unroll
        for (int dx = 0; dx < 7; ++dx) {
            const float wgt = wk[dy * 7 + dx];
            #pragma unroll
            for (int xx = 0; xx < 16; ++xx)
                acc[xx] = fmaf(wgt, win[xx + dx], acc[xx]);
        }
    }

    float* dst = pebuf + (((size_t)bc) << 12) + y * 64 + x0;
    #pragma unroll
    for (int w4 = 0; w4 < 4; ++w4)
        *reinterpret_cast<f32x4*>(dst + w4 * 4) =
            *reinterpret_cast<const f32x4*>(&acc[w4 * 4]);
}

// ---------------------------------------------------------------------------
// Kernel 4: proj GEMM with exact f32 split-K combine.  (r13 text, frozen)
// ---------------------------------------------------------------------------
__global__ __launch_bounds__(256) void proj_gemm(const float* __restrict__ O0b,
                                                 const float* __restrict__ O1b,
                                                 const float* __restrict__ L0,
                                                 const float* __restrict__ M0,
                                                 const float* __restrict__ L1,
                                                 const float* __restrict__ M1,
                                                 const float* __restrict__ PE,
                                                 const float* __restrict__ W,
                                                 const float* __restrict__ bias,
                                                 float* __restrict__ out) {
    __shared__ union {
        struct { short A[64][40]; short B[64][40]; } s;
        float T[64][65];
    } u;
    const int t = threadIdx.x;
    const int wv = t >> 6, lane = t & 63;
    const int g = lane >> 4, cc = lane & 15;
    const int wg = blockIdx.x;
    const int hi = wg / 32, rem = wg % 32;
    const int R0 = (hi * 8 + (rem & 7)) * 64;
    const int col0 = (rem >> 3) * 64;
    const int b = R0 >> 12, n0 = R0 & 4095;
    const int a_i  = t >> 2;
    const int a_kp = (t & 3) * 8;
    f32x4 acc[4] = {};

    for (int k0 = 0; k0 < 256; k0 += 32) {
        __syncthreads();
        {
            const int row = R0 + a_i;
            const int hh8 = (k0 + a_kp) >> 5;       // head for these 8 channels
            const int lmix = row * 8 + hh8;
            const float M0v = M0[lmix], M1v = M1[lmix];
            const float mstar = fmaxf(M0v, M1v);
            const float f0 = fexp2(M0v - mstar);
            const float f1 = fexp2(M1v - mstar);
            const float invl = 1.0f / (L0[lmix] * f0 + L1[lmix] * f1);
            const float c0 = f0 * invl, c1 = f1 * invl;
            const float* p0 = O0b + (size_t)row * 256 + k0 + a_kp;
            const float* p1 = O1b + (size_t)row * 256 + k0 + a_kp;
            const float4 x0lo = *reinterpret_cast<const float4*>(p0);
            const float4 x0hi = *reinterpret_cast<const float4*>(p0 + 4);
            const float4 x1lo = *reinterpret_cast<const float4*>(p1);
            const float4 x1hi = *reinterpret_cast<const float4*>(p1 + 4);
            const float* pp = PE + (((size_t)(b * 256 + k0 + a_kp)) << 12) + n0 + a_i;
            bf16x8 pk;
            pk[0] = f2bf(x0lo.x * c0 + x1lo.x * c1 + pp[0]);
            pk[1] = f2bf(x0lo.y * c0 + x1lo.y * c1 + pp[(size_t)1 << 12]);
            pk[2] = f2bf(x0lo.z * c0 + x1lo.z * c1 + pp[(size_t)2 << 12]);
            pk[3] = f2bf(x0lo.w * c0 + x1lo.w * c1 + pp[(size_t)3 << 12]);
            pk[4] = f2bf(x0hi.x * c0 + x1hi.x * c1 + pp[(size_t)4 << 12]);
            pk[5] = f2bf(x0hi.y * c0 + x1hi.y * c1 + pp[(size_t)5 << 12]);
            pk[6] = f2bf(x0hi.z * c0 + x1hi.z * c1 + pp[(size_t)6 << 12]);
            pk[7] = f2bf(x0hi.w * c0 + x1hi.w * c1 + pp[(size_t)7 << 12]);
            *reinterpret_cast<bf16x8*>(&u.s.A[a_i][a_kp]) = pk;

            const float* wp = W + (size_t)(col0 + a_i) * 256 + k0 + a_kp;
            const float4 w0 = *reinterpret_cast<const float4*>(wp);
            const float4 w1 = *reinterpret_cast<const float4*>(wp + 4);
            bf16x8 pw;
            pw[0] = f2bf(w0.x); pw[1] = f2bf(w0.y); pw[2] = f2bf(w0.z); pw[3] = f2bf(w0.w);
            pw[4] = f2bf(w1.x); pw[5] = f2bf(w1.y); pw[6] = f2bf(w1.z); pw[7] = f2bf(w1.w);
            *reinterpret_cast<bf16x8*>(&u.s.B[a_i][a_kp]) = pw;
        }
        __syncthreads();
        const bf16x8 af = *reinterpret_cast<const bf16x8*>(&u.s.A[wv * 16 + cc][g * 8]);
        #pragma unroll
        for (int nt = 0; nt < 4; ++nt) {
            const bf16x8 bfr = *reinterpret_cast<const bf16x8*>(&u.s.B[nt * 16 + cc][g * 8]);
            acc[nt] = __builtin_amdgcn_mfma_f32_16x16x32_bf16(af, bfr, acc[nt], 0, 0, 0);
        }
    }
    __syncthreads();
    #pragma unroll
    for (int nt = 0; nt < 4; ++nt) {
        const float bv = bias[col0 + nt * 16 + cc];
        #pragma unroll
        for (int r = 0; r < 4; ++r)
            u.T[nt * 16 + cc][wv * 16 + g * 4 + r] = acc[nt][r] + bv;
    }
    __syncthreads();
    #pragma unroll
    for (int it = 0; it < 16; ++it) {
        const int idx = it * 256 + t;
        const int ccc = idx >> 6, rr = idx & 63;
        out[(((size_t)(b * 256 + col0 + ccc)) << 12) + n0 + rr] = u.T[ccc][rr];
    }
}

// ---------------------------------------------------------------------------
extern "C" void kernel_launch(void* const* d_in, const int* in_sizes, int n_in,
                              void* d_out, int out_size, void* d_ws, size_t ws_size,
                              hipStream_t stream) {
    const float* x      = (const float*)d_in[0];
    const float* w_qkv  = (const float*)d_in[1];
    const float* b_qkv  = (const float*)d_in[2];
    const float* w_pe   = (const float*)d_in[3];
    const float* b_pe   = (const float*)d_in[4];
    const float* w_proj = (const float*)d_in[5];
    const float* b_proj = (const float*)d_in[6];
    float* out = (float*)d_out;

    char* ws = (char*)d_ws;
    u16*   qk    = (u16*)ws;                    // 16,777,216 B (dead after attn)
    float* pe    = (float*)ws;                  // 16,777,216 B (written after attn)
    float* o0    = (float*)(ws + 16777216);     // 16,777,216 B
    float* o1    = (float*)(ws + 33554432);     // 16,777,216 B
    u16*   vt    = (u16*)(ws + 50331648);       //  8,388,608 B
    float* l0    = (float*)(ws + 58720256);     //    524,288 B
    float* m0    = (float*)(ws + 59244544);
    float* l1    = (float*)(ws + 59768832);
    float* m1    = (float*)(ws + 60293120);     // end 60,817,408

    qkv_gemm<<<3072, 256, 0, stream>>>(x, w_qkv, b_qkv, qk, vt);
    attn_kernel<<<dim3(8, 8, 32), 256, 0, stream>>>(qk, vt, o0, o1, l0, m0, l1, m1);
    pe_conv<<<1024, 256, 0, stream>>>(vt, w_pe, b_pe, pe);
    proj_gemm<<<1024, 256, 0, stream>>>(o0, o1, l0, m0, l1, m1, pe,
                                        w_proj, b_proj, out);
}

// Round 15
// 108.519 us; speedup vs baseline: 1.1049x; 1.0009x over previous
//
#include <hip/hip_runtime.h>
#include <hip/hip_bf16.h>

// ---------------------------------------------------------------------------
// AAttn (area attention) fused pipeline for MI355X (gfx950)
//  x -> qkv conv1x1 (QK bf16 + V in NCHW bf16; packed-dword A-staging) ->
//  split-K flash attention (2x512 keys, f32 unnormalized partials, frozen
//  online-max softmax, lane-partial denominator, LDS DOUBLE-BUFFER with one
//  barrier per tile) -> pe_conv (dwconv7 on V, f32, over dead QK region) ->
//  proj conv1x1 with exact f32 split-K combine fused into A-staging.
// Workspace (60.8 MB of 64 MiB), temporal reuse @0:
//   QK  bf16 [16384][512] @0        16.78MB  (dead after attn)
//   PE  f32  [1024][4096] @0        16.78MB  (pe_conv writes after attn)
//   O0  f32  [16384][256] @16777216 16.78MB
//   O1  f32  [16384][256] @33554432 16.78MB
//   VT  bf16 [1024][4096] @50331648  8.39MB
//   L0/M0/L1/M1 f32 [131072] @58720256/59244544/59768832/60293120
// ---------------------------------------------------------------------------

typedef __attribute__((ext_vector_type(8))) short bf16x8;
typedef __attribute__((ext_vector_type(4))) short bf16x4;
typedef __attribute__((ext_vector_type(8))) unsigned short u16x8;
typedef __attribute__((ext_vector_type(4))) float f32x4;
typedef unsigned short u16;

__device__ __forceinline__ short f2bf(float f) {
    unsigned u = __builtin_bit_cast(unsigned, f);
    u = u + 0x7fffu + ((u >> 16) & 1u);   // RNE
    return (short)(u >> 16);
}
__device__ __forceinline__ float bf2f(u16 u) {
    return __builtin_bit_cast(float, (unsigned)u << 16);
}
__device__ __forceinline__ float fexp2(float x) {
#if __has_builtin(__builtin_amdgcn_exp2f)
    return __builtin_amdgcn_exp2f(x);
#else
    return exp2f(x);
#endif
}
__device__ __forceinline__ unsigned cvt_pk_bf16(float lo, float hi) {
    unsigned r;
    asm("v_cvt_pk_bf16_f32 %0, %1, %2" : "=v"(r) : "v"(lo), "v"(hi));
    return r;
}

// ---------------------------------------------------------------------------
// Kernel 1: QKV GEMM -> QK bf16 [16384][512] + V to NCHW VT.  (r13 frozen)
// ---------------------------------------------------------------------------
__global__ __launch_bounds__(256) void qkv_gemm(const float* __restrict__ X,
                                                const float* __restrict__ W,
                                                const float* __restrict__ bias,
                                                u16* __restrict__ qkout,
                                                u16* __restrict__ Vt) {
    __shared__ unsigned A32[64][22];   // [row(n)][chan-pair] packed 2xbf16
    __shared__ short Blds[64][40];
    const int t = threadIdx.x;
    const int wv = t >> 6, lane = t & 63;
    const int g = lane >> 4, cc = lane & 15;
    const int wg = blockIdx.x;
    const int hi = wg / 96, rem = wg % 96;
    const int R0 = (hi * 8 + (rem & 7)) * 64;
    const int col0 = (rem >> 3) * 64;
    const int b = R0 >> 12, n0 = R0 & 4095;
    f32x4 acc[4] = {};

    const int a_qi = t >> 4;          // 0..15: channel pair (2qi, 2qi+1)
    const int a_ii = (t & 15) * 4;    // rows n offset
    const int b_col = t >> 2;         // 0..63
    const int b_kp  = (t & 3) * 8;    // 0,8,16,24

    for (int k0 = 0; k0 < 256; k0 += 32) {
        __syncthreads();
        {   // stage A: 2 coalesced float4 loads (channels 2qi, 2qi+1) -> dwords
            const float* xp = X + (((size_t)(b * 256 + k0 + 2 * a_qi)) << 12) + n0 + a_ii;
            const float4 v0 = *reinterpret_cast<const float4*>(xp);
            const float4 v1 = *reinterpret_cast<const float4*>(xp + 4096);
            A32[a_ii + 0][a_qi] = cvt_pk_bf16(v0.x, v1.x);
            A32[a_ii + 1][a_qi] = cvt_pk_bf16(v0.y, v1.y);
            A32[a_ii + 2][a_qi] = cvt_pk_bf16(v0.z, v1.z);
            A32[a_ii + 3][a_qi] = cvt_pk_bf16(v0.w, v1.w);
        }
        {   // stage B: W[col][k] contiguous -> one b128 store
            const float* wp = W + (size_t)(col0 + b_col) * 256 + k0 + b_kp;
            const float4 v0 = *reinterpret_cast<const float4*>(wp);
            const float4 v1 = *reinterpret_cast<const float4*>(wp + 4);
            unsigned pk[4];
            pk[0] = cvt_pk_bf16(v0.x, v0.y);
            pk[1] = cvt_pk_bf16(v0.z, v0.w);
            pk[2] = cvt_pk_bf16(v1.x, v1.y);
            pk[3] = cvt_pk_bf16(v1.z, v1.w);
            *reinterpret_cast<uint4*>(&Blds[b_col][b_kp]) =
                *reinterpret_cast<const uint4*>(pk);
        }
        __syncthreads();
        union { unsigned u[4]; bf16x8 v; } afu;
        {
            const unsigned* ap = &A32[wv * 16 + cc][g * 4];
            const uint2 lo = *reinterpret_cast<const uint2*>(ap);
            const uint2 hi2 = *reinterpret_cast<const uint2*>(ap + 2);
            afu.u[0] = lo.x; afu.u[1] = lo.y; afu.u[2] = hi2.x; afu.u[3] = hi2.y;
        }
        #pragma unroll
        for (int nt = 0; nt < 4; ++nt) {
            const bf16x8 bfr = *reinterpret_cast<const bf16x8*>(&Blds[nt * 16 + cc][g * 8]);
            acc[nt] = __builtin_amdgcn_mfma_f32_16x16x32_bf16(afu.v, bfr, acc[nt], 0, 0, 0);
        }
    }
    #pragma unroll
    for (int nt = 0; nt < 4; ++nt) {
        const int col = col0 + nt * 16 + cc;
        const float bv = bias[col];
        const int m96 = col % 96;
        const int head = col / 96;
        const bool isv = (m96 >= 64);
        #pragma unroll
        for (int r = 0; r < 4; ++r) {
            const int row = R0 + wv * 16 + g * 4 + r;
            const u16 val = (u16)f2bf(acc[nt][r] + bv);
            if (isv)
                Vt[(((size_t)(b * 256 + head * 32 + (m96 - 64))) << 12) + (row & 4095)] = val;
            else
                qkout[(size_t)row * 512 + head * 64 + m96] = val;
        }
    }
}

// ---------------------------------------------------------------------------
// Kernel 2: split-K flash attention.  r14 text; ONE change: LDS K/V double-
// buffer with a single barrier per tile.  Safety: a wave stores buf[i&1] at
// iter i only after passing barrier i-1, which (program order) guarantees all
// waves finished reading buf[i&1] at iter i-2.
// ---------------------------------------------------------------------------
__global__ __launch_bounds__(256) void attn_kernel(const u16* __restrict__ QK,
                                                   const u16* __restrict__ VT,
                                                   float* __restrict__ O0,
                                                   float* __restrict__ O1,
                                                   float* __restrict__ L0,
                                                   float* __restrict__ M0,
                                                   float* __restrict__ L1,
                                                   float* __restrict__ M1) {
    __shared__ u16 Klds[2][64][32];
    __shared__ u16 Vlds[2][32][68];
    const int t = threadIdx.x;
    const int wv = t >> 6, lane = t & 63;
    const int g = lane >> 4, cc = lane & 15;
    const int h  = blockIdx.x;           // 0..7   (fastest -> determines XCD)
    const int qc = blockIdx.y;           // 0..7  (128 q rows per block)
    const int zz = blockIdx.z;           // 0..31
    const int ba = zz >> 1, half = zz & 1;
    const int koff = half * 512;
    float* Oh = half ? O1 : O0;
    float* Lh = half ? L1 : L0;
    float* Mh = half ? M1 : M0;
    const float SCALE = 0.17677669529663687f * 1.44269504088896340736f;
    const size_t qkbase = (size_t)(ba * 1024) * 512 + h * 64;

    bf16x8 qf[2];
    #pragma unroll
    for (int s = 0; s < 2; ++s) {
        const u16x8 qr = *reinterpret_cast<const u16x8*>(
            QK + qkbase + (size_t)(qc * 128 + s * 64 + wv * 16 + cc) * 512 + g * 8);
        #pragma unroll
        for (int j = 0; j < 8; ++j) qf[s][j] = f2bf(bf2f(qr[j]) * SCALE);
    }

    f32x4 o[2][2] = {};
    float m[2] = {-3e38f, -3e38f}, l[2] = {0.f, 0.f};   // l is lane-partial

    const int key_s = t >> 2;            // 0..63
    const int dp    = (t & 3) * 8;       // 0,8,16,24
    const u16* kgp = QK + qkbase + (size_t)(koff + key_s) * 512 + 32 + dp;
    const int vd  = t >> 3;              // 0..31
    const int vx8 = (t & 7) * 8;         // 0..56
    const int b_img = ba >> 2, area = ba & 3;
    const u16* vgp = VT + (((size_t)(b_img * 256 + h * 32 + vd)) << 12)
                        + area * 1024 + koff + vx8;

    u16x8 kpre = *reinterpret_cast<const u16x8*>(kgp);
    u16x8 vpre = *reinterpret_cast<const u16x8*>(vgp);

    for (int kt = 0; kt < 8; ++kt) {
        const int cur = kt & 1;
        *reinterpret_cast<u16x8*>(&Klds[cur][key_s][dp]) = kpre;
        *reinterpret_cast<u16x8*>(&Vlds[cur][vd][vx8])   = vpre;
        __syncthreads();
        if (kt < 7) {   // prefetch next tile into regs
            kpre = *reinterpret_cast<const u16x8*>(kgp + (size_t)(kt + 1) * 64 * 512);
            vpre = *reinterpret_cast<const u16x8*>(vgp + (kt + 1) * 64);
        }

        bf16x8 kf[4];
        #pragma unroll
        for (int t16 = 0; t16 < 4; ++t16)
            kf[t16] = *reinterpret_cast<const bf16x8*>(&Klds[cur][t16 * 16 + cc][g * 8]);
        bf16x8 va[2][2];
        #pragma unroll
        for (int hh = 0; hh < 2; ++hh)
            #pragma unroll
            for (int kg = 0; kg < 2; ++kg) {
                const bf16x4 lo = *reinterpret_cast<const bf16x4*>(&Vlds[cur][hh * 16 + cc][kg * 32 + 4 * g]);
                const bf16x4 hi = *reinterpret_cast<const bf16x4*>(&Vlds[cur][hh * 16 + cc][kg * 32 + 16 + 4 * g]);
                va[hh][kg] = __builtin_shufflevector(lo, hi, 0, 1, 2, 3, 4, 5, 6, 7);
            }

        #pragma unroll
        for (int s = 0; s < 2; ++s) {
            const f32x4 z = {};
            f32x4 sc[4];
            #pragma unroll
            for (int t16 = 0; t16 < 4; ++t16)
                sc[t16] = __builtin_amdgcn_mfma_f32_16x16x32_bf16(kf[t16], qf[s], z, 0, 0, 0);

            float mt = sc[0][0];
            #pragma unroll
            for (int t16 = 0; t16 < 4; ++t16)
                #pragma unroll
                for (int r = 0; r < 4; ++r) mt = fmaxf(mt, sc[t16][r]);
            mt = fmaxf(mt, __shfl_xor(mt, 16, 64));
            mt = fmaxf(mt, __shfl_xor(mt, 32, 64));
            const float mn = fmaxf(m[s], mt);
            const float fac = fexp2(m[s] - mn);
            m[s] = mn;

            float p[4][4];
            float rs = 0.f;
            #pragma unroll
            for (int t16 = 0; t16 < 4; ++t16)
                #pragma unroll
                for (int r = 0; r < 4; ++r) {
                    p[t16][r] = fexp2(sc[t16][r] - mn);
                    rs += p[t16][r];
                }
            l[s] = l[s] * fac + rs;     // lane-partial (fac uniform per q-group)
            o[s][0] *= fac;
            o[s][1] *= fac;

            union PW { int w[4]; bf16x8 v; } pb0, pb1;
            pb0.w[0] = (int)cvt_pk_bf16(p[0][0], p[0][1]);
            pb0.w[1] = (int)cvt_pk_bf16(p[0][2], p[0][3]);
            pb0.w[2] = (int)cvt_pk_bf16(p[1][0], p[1][1]);
            pb0.w[3] = (int)cvt_pk_bf16(p[1][2], p[1][3]);
            pb1.w[0] = (int)cvt_pk_bf16(p[2][0], p[2][1]);
            pb1.w[1] = (int)cvt_pk_bf16(p[2][2], p[2][3]);
            pb1.w[2] = (int)cvt_pk_bf16(p[3][0], p[3][1]);
            pb1.w[3] = (int)cvt_pk_bf16(p[3][2], p[3][3]);

            o[s][0] = __builtin_amdgcn_mfma_f32_16x16x32_bf16(va[0][0], pb0.v, o[s][0], 0, 0, 0);
            o[s][0] = __builtin_amdgcn_mfma_f32_16x16x32_bf16(va[0][1], pb1.v, o[s][0], 0, 0, 0);
            o[s][1] = __builtin_amdgcn_mfma_f32_16x16x32_bf16(va[1][0], pb0.v, o[s][1], 0, 0, 0);
            o[s][1] = __builtin_amdgcn_mfma_f32_16x16x32_bf16(va[1][1], pb1.v, o[s][1], 0, 0, 0);
        }
        __syncthreads();   // all reads of buf[cur] complete before it is re-stored
    }

    // epilogue: reduce lane-partial l across the 4-lane q-group, store O,l,m
    #pragma unroll
    for (int s = 0; s < 2; ++s) {
        l[s] += __shfl_xor(l[s], 16, 64);
        l[s] += __shfl_xor(l[s], 32, 64);
        const int q = qc * 128 + s * 64 + wv * 16 + cc;
        const int row = ba * 1024 + q;
        float* op = Oh + (size_t)row * 256 + h * 32;
        *reinterpret_cast<f32x4*>(op + 4 * g)      = o[s][0];   // d = 4g..4g+3
        *reinterpret_cast<f32x4*>(op + 16 + 4 * g) = o[s][1];   // d = 16+4g..+3
        if (g == 0) {
            const int idx = row * 8 + h;
            Lh[idx] = l[s];
            Mh[idx] = m[s];
        }
    }
}

// ---------------------------------------------------------------------------
// Kernel 3: pe_conv (r13 text, frozen).  Writes PE over dead QK region.
// ---------------------------------------------------------------------------
__global__ __launch_bounds__(256) void pe_conv(const u16* __restrict__ Vt,
                                               const float* __restrict__ wpe,
                                               const float* __restrict__ bpe,
                                               float* __restrict__ pebuf) {
    __shared__ __align__(16) float P[70][76];
    const int t = threadIdx.x;
    const int bc = blockIdx.x;             // b*256 + c
    const int c = bc & 255;

    {
        f32x4 z = {};
        f32x4* p4 = reinterpret_cast<f32x4*>(&P[0][0]);
        #pragma unroll
        for (int i = 0; i < 6; ++i) {
            const int idx = t + i * 256;
            if (idx < 1330) p4[idx] = z;
        }
    }
    __syncthreads();
    {
        const int row = t >> 2, xo = (t & 3) * 16;
        const u16* src = Vt + (((size_t)bc) << 12) + row * 64 + xo;
        const u16x8 v0 = *reinterpret_cast<const u16x8*>(src);
        const u16x8 v1 = *reinterpret_cast<const u16x8*>(src + 8);
        #pragma unroll
        for (int j = 0; j < 8; ++j) {
            P[row + 3][xo + 3 + j]  = bf2f(v0[j]);
            P[row + 3][xo + 11 + j] = bf2f(v1[j]);
        }
    }
    float wk[49];
    #pragma unroll
    for (int i = 0; i < 49; ++i) wk[i] = wpe[c * 49 + i];
    const float bias = bpe[c];
    __syncthreads();

    const int y = t >> 2, x0 = (t & 3) * 16;
    float acc[16];
    #pragma unroll
    for (int j = 0; j < 16; ++j) acc[j] = bias;

    #pragma unroll
    for (int dy = 0; dy < 7; ++dy) {
        float win[24];
        #pragma unroll
        for (int w4 = 0; w4 < 6; ++w4)
            *reinterpret_cast<f32x4*>(&win[w4 * 4]) =
                *reinterpret_cast<const f32x4*>(&P[y + dy][x0 + w4 * 4]);
        #pragma unroll
        for (int dx = 0; dx < 7; ++dx) {
            const float wgt = wk[dy * 7 + dx];
            #pragma unroll
            for (int xx = 0; xx < 16; ++xx)
                acc[xx] = fmaf(wgt, win[xx + dx], acc[xx]);
        }
    }

    float* dst = pebuf + (((size_t)bc) << 12) + y * 64 + x0;
    #pragma unroll
    for (int w4 = 0; w4 < 4; ++w4)
        *reinterpret_cast<f32x4*>(dst + w4 * 4) =
            *reinterpret_cast<const f32x4*>(&acc[w4 * 4]);
}

// ---------------------------------------------------------------------------
// Kernel 4: proj GEMM with exact f32 split-K combine.  (r13 text, frozen)
// ---------------------------------------------------------------------------
__global__ __launch_bounds__(256) void proj_gemm(const float* __restrict__ O0b,
                                                 const float* __restrict__ O1b,
                                                 const float* __restrict__ L0,
                                                 const float* __restrict__ M0,
                                                 const float* __restrict__ L1,
                                                 const float* __restrict__ M1,
                                                 const float* __restrict__ PE,
                                                 const float* __restrict__ W,
                                                 const float* __restrict__ bias,
                                                 float* __restrict__ out) {
    __shared__ union {
        struct { short A[64][40]; short B[64][40]; } s;
        float T[64][65];
    } u;
    const int t = threadIdx.x;
    const int wv = t >> 6, lane = t & 63;
    const int g = lane >> 4, cc = lane & 15;
    const int wg = blockIdx.x;
    const int hi = wg / 32, rem = wg % 32;
    const int R0 = (hi * 8 + (rem & 7)) * 64;
    const int col0 = (rem >> 3) * 64;
    const int b = R0 >> 12, n0 = R0 & 4095;
    const int a_i  = t >> 2;
    const int a_kp = (t & 3) * 8;
    f32x4 acc[4] = {};

    for (int k0 = 0; k0 < 256; k0 += 32) {
        __syncthreads();
        {
            const int row = R0 + a_i;
            const int hh8 = (k0 + a_kp) >> 5;       // head for these 8 channels
            const int lmix = row * 8 + hh8;
            const float M0v = M0[lmix], M1v = M1[lmix];
            const float mstar = fmaxf(M0v, M1v);
            const float f0 = fexp2(M0v - mstar);
            const float f1 = fexp2(M1v - mstar);
            const float invl = 1.0f / (L0[lmix] * f0 + L1[lmix] * f1);
            const float c0 = f0 * invl, c1 = f1 * invl;
            const float* p0 = O0b + (size_t)row * 256 + k0 + a_kp;
            const float* p1 = O1b + (size_t)row * 256 + k0 + a_kp;
            const float4 x0lo = *reinterpret_cast<const float4*>(p0);
            const float4 x0hi = *reinterpret_cast<const float4*>(p0 + 4);
            const float4 x1lo = *reinterpret_cast<const float4*>(p1);
            const float4 x1hi = *reinterpret_cast<const float4*>(p1 + 4);
            const float* pp = PE + (((size_t)(b * 256 + k0 + a_kp)) << 12) + n0 + a_i;
            bf16x8 pk;
            pk[0] = f2bf(x0lo.x * c0 + x1lo.x * c1 + pp[0]);
            pk[1] = f2bf(x0lo.y * c0 + x1lo.y * c1 + pp[(size_t)1 << 12]);
            pk[2] = f2bf(x0lo.z * c0 + x1lo.z * c1 + pp[(size_t)2 << 12]);
            pk[3] = f2bf(x0lo.w * c0 + x1lo.w * c1 + pp[(size_t)3 << 12]);
            pk[4] = f2bf(x0hi.x * c0 + x1hi.x * c1 + pp[(size_t)4 << 12]);
            pk[5] = f2bf(x0hi.y * c0 + x1hi.y * c1 + pp[(size_t)5 << 12]);
            pk[6] = f2bf(x0hi.z * c0 + x1hi.z * c1 + pp[(size_t)6 << 12]);
            pk[7] = f2bf(x0hi.w * c0 + x1hi.w * c1 + pp[(size_t)7 << 12]);
            *reinterpret_cast<bf16x8*>(&u.s.A[a_i][a_kp]) = pk;

            const float* wp = W + (size_t)(col0 + a_i) * 256 + k0 + a_kp;
            const float4 w0 = *reinterpret_cast<const float4*>(wp);
            const float4 w1 = *reinterpret_cast<const float4*>(wp + 4);
            bf16x8 pw;
            pw[0] = f2bf(w0.x); pw[1] = f2bf(w0.y); pw[2] = f2bf(w0.z); pw[3] = f2bf(w0.w);
            pw[4] = f2bf(w1.x); pw[5] = f2bf(w1.y); pw[6] = f2bf(w1.z); pw[7] = f2bf(w1.w);
            *reinterpret_cast<bf16x8*>(&u.s.B[a_i][a_kp]) = pw;
        }
        __syncthreads();
        const bf16x8 af = *reinterpret_cast<const bf16x8*>(&u.s.A[wv * 16 + cc][g * 8]);
        #pragma unroll
        for (int nt = 0; nt < 4; ++nt) {
            const bf16x8 bfr = *reinterpret_cast<const bf16x8*>(&u.s.B[nt * 16 + cc][g * 8]);
            acc[nt] = __builtin_amdgcn_mfma_f32_16x16x32_bf16(af, bfr, acc[nt], 0, 0, 0);
        }
    }
    __syncthreads();
    #pragma unroll
    for (int nt = 0; nt < 4; ++nt) {
        const float bv = bias[col0 + nt * 16 + cc];
        #pragma unroll
        for (int r = 0; r < 4; ++r)
            u.T[nt * 16 + cc][wv * 16 + g * 4 + r] = acc[nt][r] + bv;
    }
    __syncthreads();
    #pragma unroll
    for (int it = 0; it < 16; ++it) {
        const int idx = it * 256 + t;
        const int ccc = idx >> 6, rr = idx & 63;
        out[(((size_t)(b * 256 + col0 + ccc)) << 12) + n0 + rr] = u.T[ccc][rr];
    }
}

// ---------------------------------------------------------------------------
extern "C" void kernel_launch(void* const* d_in, const int* in_sizes, int n_in,
                              void* d_out, int out_size, void* d_ws, size_t ws_size,
                              hipStream_t stream) {
    const float* x      = (const float*)d_in[0];
    const float* w_qkv  = (const float*)d_in[1];
    const float* b_qkv  = (const float*)d_in[2];
    const float* w_pe   = (const float*)d_in[3];
    const float* b_pe   = (const float*)d_in[4];
    const float* w_proj = (const float*)d_in[5];
    const float* b_proj = (const float*)d_in[6];
    float* out = (float*)d_out;

    char* ws = (char*)d_ws;
    u16*   qk    = (u16*)ws;                    // 16,777,216 B (dead after attn)
    float* pe    = (float*)ws;                  // 16,777,216 B (written after attn)
    float* o0    = (float*)(ws + 16777216);     // 16,777,216 B
    float* o1    = (float*)(ws + 33554432);     // 16,777,216 B
    u16*   vt    = (u16*)(ws + 50331648);       //  8,388,608 B
    float* l0    = (float*)(ws + 58720256);     //    524,288 B
    float* m0    = (float*)(ws + 59244544);
    float* l1    = (float*)(ws + 59768832);
    float* m1    = (float*)(ws + 60293120);     // end 60,817,408

    qkv_gemm<<<3072, 256, 0, stream>>>(x, w_qkv, b_qkv, qk, vt);
    attn_kernel<<<dim3(8, 8, 32), 256, 0, stream>>>(qk, vt, o0, o1, l0, m0, l1, m1);
    pe_conv<<<1024, 256, 0, stream>>>(vt, w_pe, b_pe, pe);
    proj_gemm<<<1024, 256, 0, stream>>>(o0, o1, l0, m0, l1, m1, pe,
                                        w_proj, b_proj, out);
}